// Round 2
// baseline (670.451 us; speedup 1.0000x reference)
//
#include <hip/hip_runtime.h>
#include <hip/hip_bf16.h>

// Fused attention forward: B=4, N=2048, C=1024, H=16, D=64.
// Pipeline: [qkv gemm -> q/k/v bf16 [B,H,N,D]] -> [flash attn -> o bf16 [B,N,C]]
//           -> [proj gemm + bias -> fp32 out].
// All matmuls via v_mfma_f32_16x16x32_bf16, fp32 accumulate.
// Verified layouts (learn_hip m89/m91): A: lane holds A[m=l&15][k=(l>>4)*8+j];
// B: lane holds B[k=(l>>4)*8+j][n=l&15]; D: lane holds D[(l>>4)*4+r][l&15].

#define B_ 4
#define N_ 2048
#define C_ 1024
#define H_ 16
#define D_ 64

typedef __attribute__((ext_vector_type(8))) __bf16 bf16x8;
typedef __attribute__((ext_vector_type(4))) float f32x4;

__device__ inline unsigned short f2bf(float f) {
  unsigned u = __float_as_uint(f);
  u += 0x7FFF + ((u >> 16) & 1);   // round-to-nearest-even
  return (unsigned short)(u >> 16);
}

// C[M,Nout] = A[M,K] @ B[K,Nout].  A row-major fp32 (or bf16 if A_BF16),
// B row-major fp32 (converted to bf16 at staging).
// MODE 0: scatter bf16 results to q/k/v buffers laid out [B,H,N,D].
// MODE 1: fp32 out = acc + bias.
template<int MODE, bool A_BF16>
__global__ __launch_bounds__(256) void gemm_kernel(
    const void* __restrict__ Aptr, const float* __restrict__ Bptr,
    const float* __restrict__ bias,
    unsigned short* __restrict__ qb, unsigned short* __restrict__ kb,
    unsigned short* __restrict__ vb, float* __restrict__ outp,
    int M, int K, int Nout)
{
  __shared__ unsigned short Al[64][72];   // [m][k], +8 pad breaks bank conflicts
  __shared__ unsigned short Bl[64][72];   // transposed: [n][k]
  const int tid = threadIdx.x;
  const int w = tid >> 6;
  const int lane = tid & 63;
  const int l15 = lane & 15, lk = lane >> 4;
  const int n0 = blockIdx.x * 64, m0 = blockIdx.y * 64;

  f32x4 acc[4];
#pragma unroll
  for (int i = 0; i < 4; i++) acc[i] = f32x4{0.f, 0.f, 0.f, 0.f};

  for (int kt = 0; kt < K; kt += 64) {
    // ---- stage A tile 64x64 -> bf16 LDS ----
    if (A_BF16) {
      const unsigned short* Ag = (const unsigned short*)Aptr;
#pragma unroll
      for (int i = 0; i < 2; i++) {
        int id = i * 256 + tid;
        int row = id >> 3, c8 = id & 7;
        *(uint4*)&Al[row][c8 * 8] =
            *(const uint4*)&Ag[(size_t)(m0 + row) * K + kt + c8 * 8];
      }
    } else {
      const float* Ag = (const float*)Aptr;
#pragma unroll
      for (int i = 0; i < 4; i++) {
        int id = i * 256 + tid;
        int row = id >> 4, c4 = id & 15;
        float4 f = *(const float4*)&Ag[(size_t)(m0 + row) * K + kt + c4 * 4];
        ushort4 h;
        h.x = f2bf(f.x); h.y = f2bf(f.y); h.z = f2bf(f.z); h.w = f2bf(f.w);
        *(ushort4*)&Al[row][c4 * 4] = h;
      }
    }
    // ---- stage B tile 64x64 transposed -> Bl[n][k] ----
#pragma unroll
    for (int i = 0; i < 4; i++) {
      int id = i * 256 + tid;
      int row = id >> 4, c4 = id & 15;           // row = k index, c4*4 = n offset
      float4 f = *(const float4*)&Bptr[(size_t)(kt + row) * Nout + n0 + c4 * 4];
      Bl[c4 * 4 + 0][row] = f2bf(f.x);
      Bl[c4 * 4 + 1][row] = f2bf(f.y);
      Bl[c4 * 4 + 2][row] = f2bf(f.z);
      Bl[c4 * 4 + 3][row] = f2bf(f.w);
    }
    __syncthreads();
#pragma unroll
    for (int kk = 0; kk < 2; kk++) {
      bf16x8 a = *(const bf16x8*)&Al[w * 16 + l15][kk * 32 + lk * 8];
#pragma unroll
      for (int nf = 0; nf < 4; nf++) {
        bf16x8 b = *(const bf16x8*)&Bl[nf * 16 + l15][kk * 32 + lk * 8];
        acc[nf] = __builtin_amdgcn_mfma_f32_16x16x32_bf16(a, b, acc[nf], 0, 0, 0);
      }
    }
    __syncthreads();
  }

  if (MODE == 0) {
    // qkv column c = t*1024 + h*64 + d ; tile (64 cols) never straddles t/h.
    const int t = n0 >> 10;
    const int h = (n0 >> 6) & 15;
    unsigned short* dst = (t == 0) ? qb : (t == 1 ? kb : vb);
#pragma unroll
    for (int nf = 0; nf < 4; nf++) {
      int d = nf * 16 + l15;
#pragma unroll
      for (int r = 0; r < 4; r++) {
        int m = m0 + w * 16 + lk * 4 + r;        // m = b*2048 + n
        int b = m >> 11, n = m & 2047;
        dst[(((size_t)(b * 16 + h)) * 2048 + n) * 64 + d] = f2bf(acc[nf][r]);
      }
    }
  } else {
#pragma unroll
    for (int nf = 0; nf < 4; nf++) {
      int c = n0 + nf * 16 + l15;
      float bv = bias[c];
#pragma unroll
      for (int r = 0; r < 4; r++) {
        int m = m0 + w * 16 + lk * 4 + r;
        outp[(size_t)m * Nout + c] = acc[nf][r] + bv;
      }
    }
  }
}

// Flash attention: one block = 64 Q rows of one (b,h). 4 waves, each owns 16 rows.
__global__ __launch_bounds__(256) void flash_kernel(
    const unsigned short* __restrict__ qb, const unsigned short* __restrict__ kb,
    const unsigned short* __restrict__ vb, unsigned short* __restrict__ ob)
{
  __shared__ unsigned short Kl[64][72];   // [kv][d]
  __shared__ unsigned short Vl[64][72];   // transposed: [d][kv]
  __shared__ unsigned short Pl[64][72];   // [qrow][kv]
  const int tid = threadIdx.x;
  const int w = tid >> 6;
  const int lane = tid & 63;
  const int l15 = lane & 15, lk = lane >> 4;
  const int q0 = blockIdx.x * 64;
  const int bh = blockIdx.y;              // b*16 + h
  const size_t base = (size_t)bh * N_ * D_;
  const unsigned short* Qg = qb + base;
  const unsigned short* Kg = kb + base;
  const unsigned short* Vg = vb + base;

  // Q fragments live in registers for the whole kernel.
  bf16x8 qf[2];
#pragma unroll
  for (int kk = 0; kk < 2; kk++)
    qf[kk] = *(const bf16x8*)&Qg[(size_t)(q0 + w * 16 + l15) * 64 + kk * 32 + lk * 8];

  f32x4 acc_o[4];
#pragma unroll
  for (int i = 0; i < 4; i++) acc_o[i] = f32x4{0.f, 0.f, 0.f, 0.f};
  float mrow[4], lrow[4];
#pragma unroll
  for (int r = 0; r < 4; r++) { mrow[r] = -1e30f; lrow[r] = 0.f; }

  for (int kv0 = 0; kv0 < N_; kv0 += 64) {
    // stage K [64][64]
#pragma unroll
    for (int i = 0; i < 2; i++) {
      int id = i * 256 + tid;
      int row = id >> 3, c8 = id & 7;
      *(uint4*)&Kl[row][c8 * 8] =
          *(const uint4*)&Kg[(size_t)(kv0 + row) * 64 + c8 * 8];
    }
    // stage V transposed -> Vl[d][kv]
#pragma unroll
    for (int i = 0; i < 2; i++) {
      int id = i * 256 + tid;
      int row = id >> 3, c8 = id & 7;
      uint4 v = *(const uint4*)&Vg[(size_t)(kv0 + row) * 64 + c8 * 8];
      const unsigned short* pv = (const unsigned short*)&v;
#pragma unroll
      for (int j = 0; j < 8; j++) Vl[c8 * 8 + j][row] = pv[j];
    }
    __syncthreads();

    // S = Q K^T  (A=Q strip, B[k=d][n=kv] = Kl row n)
    f32x4 sa[4];
#pragma unroll
    for (int i = 0; i < 4; i++) sa[i] = f32x4{0.f, 0.f, 0.f, 0.f};
#pragma unroll
    for (int kk = 0; kk < 2; kk++) {
#pragma unroll
      for (int nf = 0; nf < 4; nf++) {
        bf16x8 b = *(const bf16x8*)&Kl[nf * 16 + l15][kk * 32 + lk * 8];
        sa[nf] = __builtin_amdgcn_mfma_f32_16x16x32_bf16(qf[kk], b, sa[nf], 0, 0, 0);
      }
    }

    // online softmax per owned row; 16-lane butterfly for row reduce
#pragma unroll
    for (int r = 0; r < 4; r++) {
      float s0 = sa[0][r] * 0.125f, s1 = sa[1][r] * 0.125f;
      float s2 = sa[2][r] * 0.125f, s3 = sa[3][r] * 0.125f;
      float mx = fmaxf(fmaxf(s0, s1), fmaxf(s2, s3));
      mx = fmaxf(mx, __shfl_xor(mx, 1));
      mx = fmaxf(mx, __shfl_xor(mx, 2));
      mx = fmaxf(mx, __shfl_xor(mx, 4));
      mx = fmaxf(mx, __shfl_xor(mx, 8));
      float mnew = fmaxf(mrow[r], mx);
      float corr = __expf(mrow[r] - mnew);
      float p0 = __expf(s0 - mnew), p1 = __expf(s1 - mnew);
      float p2 = __expf(s2 - mnew), p3 = __expf(s3 - mnew);
      float rs = p0 + p1 + p2 + p3;
      rs += __shfl_xor(rs, 1);
      rs += __shfl_xor(rs, 2);
      rs += __shfl_xor(rs, 4);
      rs += __shfl_xor(rs, 8);
      lrow[r] = lrow[r] * corr + rs;
      mrow[r] = mnew;
#pragma unroll
      for (int nf = 0; nf < 4; nf++) acc_o[nf][r] *= corr;
      int prow = w * 16 + lk * 4 + r;
      Pl[prow][0 + l15]  = f2bf(p0);
      Pl[prow][16 + l15] = f2bf(p1);
      Pl[prow][32 + l15] = f2bf(p2);
      Pl[prow][48 + l15] = f2bf(p3);
    }
    __syncthreads();

    // O += P V   (A = own P rows, B[k=kv][n=d] = Vl row n)
#pragma unroll
    for (int kk = 0; kk < 2; kk++) {
      bf16x8 a = *(const bf16x8*)&Pl[w * 16 + l15][kk * 32 + lk * 8];
#pragma unroll
      for (int nf = 0; nf < 4; nf++) {
        bf16x8 b = *(const bf16x8*)&Vl[nf * 16 + l15][kk * 32 + lk * 8];
        acc_o[nf] = __builtin_amdgcn_mfma_f32_16x16x32_bf16(a, b, acc_o[nf], 0, 0, 0);
      }
    }
    __syncthreads();
  }

  // epilogue: O /= l ; write o as [B,N,H,D] (== [B,N,C])
  const int b = bh >> 4, h = bh & 15;
#pragma unroll
  for (int r = 0; r < 4; r++) {
    float inv = 1.0f / lrow[r];
    int n = q0 + w * 16 + lk * 4 + r;
    size_t obase = (((size_t)b * N_ + n) * H_ + h) * D_;
#pragma unroll
    for (int nf = 0; nf < 4; nf++)
      ob[obase + nf * 16 + l15] = f2bf(acc_o[nf][r] * inv);
  }
}

extern "C" void kernel_launch(void* const* d_in, const int* in_sizes, int n_in,
                              void* d_out, int out_size, void* d_ws, size_t ws_size,
                              hipStream_t stream) {
  const float* x      = (const float*)d_in[0];
  const float* w_qkv  = (const float*)d_in[1];
  const float* w_proj = (const float*)d_in[2];
  const float* b_proj = (const float*)d_in[3];
  float* out = (float*)d_out;

  const size_t qsz = (size_t)B_ * H_ * N_ * D_;   // 8388608 elems
  unsigned short* qb = (unsigned short*)d_ws;      // 16 MB each
  unsigned short* kb = qb + qsz;
  unsigned short* vb = kb + qsz;
  unsigned short* ob = vb + qsz;                   // o as [B,N,C] bf16

  // 1) qkv = x @ w_qkv  (M=8192, K=1024, N=3072), scatter to q/k/v [B,H,N,D]
  gemm_kernel<0, false><<<dim3(3072 / 64, 8192 / 64), 256, 0, stream>>>(
      x, w_qkv, nullptr, qb, kb, vb, nullptr, 8192, 1024, 3072);

  // 2) flash attention per (b,h), 64-row Q tiles
  flash_kernel<<<dim3(N_ / 64, B_ * H_), 256, 0, stream>>>(qb, kb, vb, ob);

  // 3) out = o @ w_proj + b_proj  (M=8192, K=1024, N=1024), fp32 out
  gemm_kernel<1, true><<<dim3(1024 / 64, 8192 / 64), 256, 0, stream>>>(
      ob, w_proj, b_proj, nullptr, nullptr, nullptr, out, 8192, 1024, 1024);
}

// Round 3
// 446.030 us; speedup vs baseline: 1.5032x; 1.5032x over previous
//
#include <hip/hip_runtime.h>
#include <hip/hip_bf16.h>

// Fused attention forward: B=4, N=2048, C=1024, H=16, D=64.
// Round 2: m97-class GEMMs (128^2 tile, BK=64, global_load_lds w16, linear LDS)
// + prep passes (x->bf16, weights->transposed bf16). Flash kernel unchanged.

#define B_ 4
#define N_ 2048
#define C_ 1024
#define H_ 16
#define D_ 64

typedef __attribute__((ext_vector_type(8))) __bf16 bf16x8;
typedef __attribute__((ext_vector_type(4))) float f32x4;
typedef unsigned int u32;

__device__ inline unsigned short f2bf(float f) {
  unsigned u = __float_as_uint(f);
  u += 0x7FFF + ((u >> 16) & 1);   // round-to-nearest-even
  return (unsigned short)(u >> 16);
}

__device__ __forceinline__ void gld16(const void* g, void* l) {
  __builtin_amdgcn_global_load_lds(
      (const __attribute__((address_space(1))) u32*)g,
      (__attribute__((address_space(3))) u32*)l, 16, 0, 0);
}

// ---- prep: fp32 -> bf16, same layout (n multiple of 2048*8) ----
__global__ __launch_bounds__(256) void cvt_bf16_kernel(
    const float* __restrict__ in, unsigned short* __restrict__ out) {
  int i = (blockIdx.x * 256 + threadIdx.x) * 8;
  float4 f0 = *(const float4*)&in[i];
  float4 f1 = *(const float4*)&in[i + 4];
  ushort4 h0, h1;
  h0.x = f2bf(f0.x); h0.y = f2bf(f0.y); h0.z = f2bf(f0.z); h0.w = f2bf(f0.w);
  h1.x = f2bf(f1.x); h1.y = f2bf(f1.y); h1.z = f2bf(f1.z); h1.w = f2bf(f1.w);
  *(ushort4*)&out[i] = h0;
  *(ushort4*)&out[i + 4] = h1;
}

// ---- prep: W[K][Nn] fp32 -> Wt[Nn][K] bf16 (32x32 tiles) ----
__global__ __launch_bounds__(256) void transpose_cvt_kernel(
    const float* __restrict__ in, unsigned short* __restrict__ out,
    int K, int Nn) {
  __shared__ float tile[32][33];
  const int t = threadIdx.x;
  const int k0 = blockIdx.y * 32, n0 = blockIdx.x * 32;
  {
    int r = t >> 3, c = (t & 7) * 4;
    float4 f = *(const float4*)&in[(size_t)(k0 + r) * Nn + n0 + c];
    tile[r][c + 0] = f.x; tile[r][c + 1] = f.y;
    tile[r][c + 2] = f.z; tile[r][c + 3] = f.w;
  }
  __syncthreads();
  {
    int nr = t >> 3, kc = (t & 7) * 4;
    ushort4 h;
    h.x = f2bf(tile[kc + 0][nr]);
    h.y = f2bf(tile[kc + 1][nr]);
    h.z = f2bf(tile[kc + 2][nr]);
    h.w = f2bf(tile[kc + 3][nr]);
    *(ushort4*)&out[(size_t)(n0 + nr) * K + k0 + kc] = h;
  }
}

// ---- m97-class GEMM: C[M,Nout] = A[M,K] @ Bt[Nout,K]^T ----
// A, Bt row-major bf16. 128x128 tile, BK=64, 4 waves each 64x64 (4x4 frags).
// MODE 0: scatter bf16 to q/k/v [B,H,N,D]. MODE 1: fp32 out = acc + bias.
template<int MODE>
__global__ __launch_bounds__(256) void gemm128_kernel(
    const unsigned short* __restrict__ A, const unsigned short* __restrict__ Bt,
    const float* __restrict__ bias,
    unsigned short* __restrict__ qb, unsigned short* __restrict__ kb,
    unsigned short* __restrict__ vb, float* __restrict__ outp,
    int M, int K, int Nout)
{
  __shared__ unsigned short Al[128 * 64];   // [m][k] linear (global_load_lds dest)
  __shared__ unsigned short Bl[128 * 64];   // [n][k] linear
  const int tid = threadIdx.x;
  const int w = tid >> 6, lane = tid & 63;
  const int l15 = lane & 15, lk = lane >> 4;
  const int wr = w >> 1, wc = w & 1;
  const int n0 = blockIdx.x * 128, m0 = blockIdx.y * 128;

  // staging coords: issue i covers rows i*32..i*32+31, thread t -> row i*32+(t>>3), col (t&7)*8
  const int srow = tid >> 3;
  const int scol = (tid & 7) * 8;

  f32x4 acc[4][4];
#pragma unroll
  for (int m = 0; m < 4; m++)
#pragma unroll
    for (int n = 0; n < 4; n++) acc[m][n] = f32x4{0.f, 0.f, 0.f, 0.f};

  for (int kt = 0; kt < K; kt += 64) {
#pragma unroll
    for (int i = 0; i < 4; i++)
      gld16(&A[(size_t)(m0 + i * 32 + srow) * K + kt + scol],
            &Al[i * 2048 + w * 512]);
#pragma unroll
    for (int i = 0; i < 4; i++)
      gld16(&Bt[(size_t)(n0 + i * 32 + srow) * K + kt + scol],
            &Bl[i * 2048 + w * 512]);
    __syncthreads();

#pragma unroll
    for (int kk = 0; kk < 2; kk++) {
      bf16x8 af[4], bf[4];
#pragma unroll
      for (int m = 0; m < 4; m++)
        af[m] = *(const bf16x8*)&Al[(wr * 64 + m * 16 + l15) * 64 + kk * 32 + lk * 8];
#pragma unroll
      for (int n = 0; n < 4; n++)
        bf[n] = *(const bf16x8*)&Bl[(wc * 64 + n * 16 + l15) * 64 + kk * 32 + lk * 8];
#pragma unroll
      for (int m = 0; m < 4; m++)
#pragma unroll
        for (int n = 0; n < 4; n++)
          acc[m][n] = __builtin_amdgcn_mfma_f32_16x16x32_bf16(af[m], bf[n], acc[m][n], 0, 0, 0);
    }
    __syncthreads();
  }

  if (MODE == 0) {
#pragma unroll
    for (int n = 0; n < 4; n++) {
      int c = n0 + wc * 64 + n * 16 + l15;          // qkv col: t*1024 + h*64 + d
      int tsel = c >> 10, h = (c >> 6) & 15, d = c & 63;
      unsigned short* dst = (tsel == 0) ? qb : (tsel == 1 ? kb : vb);
#pragma unroll
      for (int m = 0; m < 4; m++) {
#pragma unroll
        for (int r = 0; r < 4; r++) {
          int row = m0 + wr * 64 + m * 16 + lk * 4 + r;   // b*2048 + n
          int b = row >> 11, nn = row & 2047;
          dst[(((size_t)(b * 16 + h)) * 2048 + nn) * 64 + d] = f2bf(acc[m][n][r]);
        }
      }
    }
  } else {
#pragma unroll
    for (int n = 0; n < 4; n++) {
      int c = n0 + wc * 64 + n * 16 + l15;
      float bv = bias[c];
#pragma unroll
      for (int m = 0; m < 4; m++) {
#pragma unroll
        for (int r = 0; r < 4; r++) {
          int row = m0 + wr * 64 + m * 16 + lk * 4 + r;
          outp[(size_t)row * Nout + c] = acc[m][n][r] + bv;
        }
      }
    }
  }
}

// ---- Flash attention (unchanged from round 1) ----
__global__ __launch_bounds__(256) void flash_kernel(
    const unsigned short* __restrict__ qb, const unsigned short* __restrict__ kb,
    const unsigned short* __restrict__ vb, unsigned short* __restrict__ ob)
{
  __shared__ unsigned short Kl[64][72];   // [kv][d]
  __shared__ unsigned short Vl[64][72];   // transposed: [d][kv]
  __shared__ unsigned short Pl[64][72];   // [qrow][kv]
  const int tid = threadIdx.x;
  const int w = tid >> 6;
  const int lane = tid & 63;
  const int l15 = lane & 15, lk = lane >> 4;
  const int q0 = blockIdx.x * 64;
  const int bh = blockIdx.y;              // b*16 + h
  const size_t base = (size_t)bh * N_ * D_;
  const unsigned short* Qg = qb + base;
  const unsigned short* Kg = kb + base;
  const unsigned short* Vg = vb + base;

  bf16x8 qf[2];
#pragma unroll
  for (int kk = 0; kk < 2; kk++)
    qf[kk] = *(const bf16x8*)&Qg[(size_t)(q0 + w * 16 + l15) * 64 + kk * 32 + lk * 8];

  f32x4 acc_o[4];
#pragma unroll
  for (int i = 0; i < 4; i++) acc_o[i] = f32x4{0.f, 0.f, 0.f, 0.f};
  float mrow[4], lrow[4];
#pragma unroll
  for (int r = 0; r < 4; r++) { mrow[r] = -1e30f; lrow[r] = 0.f; }

  for (int kv0 = 0; kv0 < N_; kv0 += 64) {
#pragma unroll
    for (int i = 0; i < 2; i++) {
      int id = i * 256 + tid;
      int row = id >> 3, c8 = id & 7;
      *(uint4*)&Kl[row][c8 * 8] =
          *(const uint4*)&Kg[(size_t)(kv0 + row) * 64 + c8 * 8];
    }
#pragma unroll
    for (int i = 0; i < 2; i++) {
      int id = i * 256 + tid;
      int row = id >> 3, c8 = id & 7;
      uint4 v = *(const uint4*)&Vg[(size_t)(kv0 + row) * 64 + c8 * 8];
      const unsigned short* pv = (const unsigned short*)&v;
#pragma unroll
      for (int j = 0; j < 8; j++) Vl[c8 * 8 + j][row] = pv[j];
    }
    __syncthreads();

    f32x4 sa[4];
#pragma unroll
    for (int i = 0; i < 4; i++) sa[i] = f32x4{0.f, 0.f, 0.f, 0.f};
#pragma unroll
    for (int kk = 0; kk < 2; kk++) {
#pragma unroll
      for (int nf = 0; nf < 4; nf++) {
        bf16x8 b = *(const bf16x8*)&Kl[nf * 16 + l15][kk * 32 + lk * 8];
        sa[nf] = __builtin_amdgcn_mfma_f32_16x16x32_bf16(qf[kk], b, sa[nf], 0, 0, 0);
      }
    }

#pragma unroll
    for (int r = 0; r < 4; r++) {
      float s0 = sa[0][r] * 0.125f, s1 = sa[1][r] * 0.125f;
      float s2 = sa[2][r] * 0.125f, s3 = sa[3][r] * 0.125f;
      float mx = fmaxf(fmaxf(s0, s1), fmaxf(s2, s3));
      mx = fmaxf(mx, __shfl_xor(mx, 1));
      mx = fmaxf(mx, __shfl_xor(mx, 2));
      mx = fmaxf(mx, __shfl_xor(mx, 4));
      mx = fmaxf(mx, __shfl_xor(mx, 8));
      float mnew = fmaxf(mrow[r], mx);
      float corr = __expf(mrow[r] - mnew);
      float p0 = __expf(s0 - mnew), p1 = __expf(s1 - mnew);
      float p2 = __expf(s2 - mnew), p3 = __expf(s3 - mnew);
      float rs = p0 + p1 + p2 + p3;
      rs += __shfl_xor(rs, 1);
      rs += __shfl_xor(rs, 2);
      rs += __shfl_xor(rs, 4);
      rs += __shfl_xor(rs, 8);
      lrow[r] = lrow[r] * corr + rs;
      mrow[r] = mnew;
#pragma unroll
      for (int nf = 0; nf < 4; nf++) acc_o[nf][r] *= corr;
      int prow = w * 16 + lk * 4 + r;
      Pl[prow][0 + l15]  = f2bf(p0);
      Pl[prow][16 + l15] = f2bf(p1);
      Pl[prow][32 + l15] = f2bf(p2);
      Pl[prow][48 + l15] = f2bf(p3);
    }
    __syncthreads();

#pragma unroll
    for (int kk = 0; kk < 2; kk++) {
      bf16x8 a = *(const bf16x8*)&Pl[w * 16 + l15][kk * 32 + lk * 8];
#pragma unroll
      for (int nf = 0; nf < 4; nf++) {
        bf16x8 b = *(const bf16x8*)&Vl[nf * 16 + l15][kk * 32 + lk * 8];
        acc_o[nf] = __builtin_amdgcn_mfma_f32_16x16x32_bf16(a, b, acc_o[nf], 0, 0, 0);
      }
    }
    __syncthreads();
  }

  const int b = bh >> 4, h = bh & 15;
#pragma unroll
  for (int r = 0; r < 4; r++) {
    float inv = 1.0f / lrow[r];
    int n = q0 + w * 16 + lk * 4 + r;
    size_t obase = (((size_t)b * N_ + n) * H_ + h) * D_;
#pragma unroll
    for (int nf = 0; nf < 4; nf++)
      ob[obase + nf * 16 + l15] = f2bf(acc_o[nf][r] * inv);
  }
}

extern "C" void kernel_launch(void* const* d_in, const int* in_sizes, int n_in,
                              void* d_out, int out_size, void* d_ws, size_t ws_size,
                              hipStream_t stream) {
  const float* x      = (const float*)d_in[0];
  const float* w_qkv  = (const float*)d_in[1];
  const float* w_proj = (const float*)d_in[2];
  const float* b_proj = (const float*)d_in[3];
  float* out = (float*)d_out;

  const size_t qsz = (size_t)B_ * H_ * N_ * D_;          // 8388608 elems
  unsigned short* qb     = (unsigned short*)d_ws;         // 16.8 MB each
  unsigned short* kb     = qb + qsz;
  unsigned short* vb     = kb + qsz;
  unsigned short* xbf    = vb + qsz;                      // x as bf16 [8192][1024]
  unsigned short* ob     = xbf;                           // alias: x dead after qkv gemm
  unsigned short* wqkv_t = xbf + qsz;                     // [3072][1024] bf16
  unsigned short* wproj_t= wqkv_t + (size_t)3072 * 1024;  // [1024][1024] bf16

  // prep: x -> bf16 ; weights -> transposed bf16
  cvt_bf16_kernel<<<4096, 256, 0, stream>>>(x, xbf);
  transpose_cvt_kernel<<<dim3(3072 / 32, 1024 / 32), 256, 0, stream>>>(w_qkv, wqkv_t, 1024, 3072);
  transpose_cvt_kernel<<<dim3(1024 / 32, 1024 / 32), 256, 0, stream>>>(w_proj, wproj_t, 1024, 1024);

  // 1) qkv = x @ w_qkv  (M=8192, K=1024, N=3072) -> scatter q/k/v [B,H,N,D]
  gemm128_kernel<0><<<dim3(3072 / 128, 8192 / 128), 256, 0, stream>>>(
      xbf, wqkv_t, nullptr, qb, kb, vb, nullptr, 8192, 1024, 3072);

  // 2) flash attention per (b,h), 64-row Q tiles  (ob aliases xbf — x is dead)
  flash_kernel<<<dim3(N_ / 64, B_ * H_), 256, 0, stream>>>(qb, kb, vb, ob);

  // 3) out = o @ w_proj + b_proj  (M=8192, K=1024, N=1024), fp32 out
  gemm128_kernel<1><<<dim3(1024 / 128, 8192 / 128), 256, 0, stream>>>(
      ob, wproj_t, b_proj, nullptr, nullptr, nullptr, out, 8192, 1024, 1024);
}

// Round 4
// 439.435 us; speedup vs baseline: 1.5257x; 1.0150x over previous
//
#include <hip/hip_runtime.h>
#include <hip/hip_bf16.h>

// Fused attention forward: B=4, N=2048, C=1024, H=16, D=64.
// Round 3: flash restructured — KVBLK=128, pre-transposed V (separate pass),
// async-stage global loads, 2 barriers/iter, scale folded into Q.
// GEMMs: m97-class 128^2 global_load_lds (unchanged from round 2).

#define B_ 4
#define N_ 2048
#define C_ 1024
#define H_ 16
#define D_ 64
#define KVB 128

typedef __attribute__((ext_vector_type(8))) __bf16 bf16x8;
typedef __attribute__((ext_vector_type(4))) float f32x4;
typedef unsigned int u32;

__device__ inline unsigned short f2bf(float f) {
  unsigned u = __float_as_uint(f);
  u += 0x7FFF + ((u >> 16) & 1);   // round-to-nearest-even
  return (unsigned short)(u >> 16);
}

__device__ __forceinline__ void gld16(const void* g, void* l) {
  __builtin_amdgcn_global_load_lds(
      (const __attribute__((address_space(1))) u32*)g,
      (__attribute__((address_space(3))) u32*)l, 16, 0, 0);
}

// ---- prep: fp32 -> bf16, same layout ----
__global__ __launch_bounds__(256) void cvt_bf16_kernel(
    const float* __restrict__ in, unsigned short* __restrict__ out) {
  int i = (blockIdx.x * 256 + threadIdx.x) * 8;
  float4 f0 = *(const float4*)&in[i];
  float4 f1 = *(const float4*)&in[i + 4];
  ushort4 h0, h1;
  h0.x = f2bf(f0.x); h0.y = f2bf(f0.y); h0.z = f2bf(f0.z); h0.w = f2bf(f0.w);
  h1.x = f2bf(f1.x); h1.y = f2bf(f1.y); h1.z = f2bf(f1.z); h1.w = f2bf(f1.w);
  *(ushort4*)&out[i] = h0;
  *(ushort4*)&out[i + 4] = h1;
}

// ---- prep: W[K][Nn] fp32 -> Wt[Nn][K] bf16 (32x32 tiles) ----
__global__ __launch_bounds__(256) void transpose_cvt_kernel(
    const float* __restrict__ in, unsigned short* __restrict__ out,
    int K, int Nn) {
  __shared__ float tile[32][33];
  const int t = threadIdx.x;
  const int k0 = blockIdx.y * 32, n0 = blockIdx.x * 32;
  {
    int r = t >> 3, c = (t & 7) * 4;
    float4 f = *(const float4*)&in[(size_t)(k0 + r) * Nn + n0 + c];
    tile[r][c + 0] = f.x; tile[r][c + 1] = f.y;
    tile[r][c + 2] = f.z; tile[r][c + 3] = f.w;
  }
  __syncthreads();
  {
    int nr = t >> 3, kc = (t & 7) * 4;
    ushort4 h;
    h.x = f2bf(tile[kc + 0][nr]);
    h.y = f2bf(tile[kc + 1][nr]);
    h.z = f2bf(tile[kc + 2][nr]);
    h.w = f2bf(tile[kc + 3][nr]);
    *(ushort4*)&out[(size_t)(n0 + nr) * K + k0 + kc] = h;
  }
}

// ---- prep: vb [bh][n][d] bf16 -> vtb [bh][d][n] bf16 (64x64 tiles) ----
// u32 LDS tile, stride 65: both phases verified 2-lanes/bank (free).
__global__ __launch_bounds__(256) void transpose_v_kernel(
    const unsigned short* __restrict__ vb, unsigned short* __restrict__ vtb) {
  __shared__ u32 tile[64][65];
  const int tid = threadIdx.x;
  const int n0 = blockIdx.x * 64;
  const int bh = blockIdx.y;
  const size_t base = (size_t)bh * N_ * D_;
#pragma unroll
  for (int i = 0; i < 2; i++) {
    int id = i * 256 + tid;
    int row = id >> 3, c8 = id & 7;            // row = n offset, c8*8 = d
    uint4 v = *(const uint4*)&vb[base + (size_t)(n0 + row) * D_ + c8 * 8];
    const unsigned short* pv = (const unsigned short*)&v;
#pragma unroll
    for (int j = 0; j < 8; j++) tile[row][c8 * 8 + j] = pv[j];
  }
  __syncthreads();
#pragma unroll
  for (int i = 0; i < 2; i++) {
    int id = i * 256 + tid;
    int d = id >> 3, nc = id & 7;              // out row d, cols nc*8..nc*8+7
    uint4 o;
    unsigned short* po = (unsigned short*)&o;
#pragma unroll
    for (int j = 0; j < 8; j++) po[j] = (unsigned short)tile[nc * 8 + j][d];
    *(uint4*)&vtb[base + (size_t)d * N_ + n0 + nc * 8] = o;
  }
}

// ---- m97-class GEMM: C[M,Nout] = A[M,K] @ Bt[Nout,K]^T ----
// MODE 0: scatter bf16 to q/k/v [B,H,N,D]; q pre-scaled by 0.125 (attn scale).
// MODE 1: fp32 out = acc + bias.
template<int MODE>
__global__ __launch_bounds__(256) void gemm128_kernel(
    const unsigned short* __restrict__ A, const unsigned short* __restrict__ Bt,
    const float* __restrict__ bias,
    unsigned short* __restrict__ qb, unsigned short* __restrict__ kb,
    unsigned short* __restrict__ vb, float* __restrict__ outp,
    int M, int K, int Nout)
{
  __shared__ unsigned short Al[128 * 64];
  __shared__ unsigned short Bl[128 * 64];
  const int tid = threadIdx.x;
  const int w = tid >> 6, lane = tid & 63;
  const int l15 = lane & 15, lk = lane >> 4;
  const int wr = w >> 1, wc = w & 1;
  const int n0 = blockIdx.x * 128, m0 = blockIdx.y * 128;
  const int srow = tid >> 3;
  const int scol = (tid & 7) * 8;

  f32x4 acc[4][4];
#pragma unroll
  for (int m = 0; m < 4; m++)
#pragma unroll
    for (int n = 0; n < 4; n++) acc[m][n] = f32x4{0.f, 0.f, 0.f, 0.f};

  for (int kt = 0; kt < K; kt += 64) {
#pragma unroll
    for (int i = 0; i < 4; i++)
      gld16(&A[(size_t)(m0 + i * 32 + srow) * K + kt + scol],
            &Al[i * 2048 + w * 512]);
#pragma unroll
    for (int i = 0; i < 4; i++)
      gld16(&Bt[(size_t)(n0 + i * 32 + srow) * K + kt + scol],
            &Bl[i * 2048 + w * 512]);
    __syncthreads();

#pragma unroll
    for (int kk = 0; kk < 2; kk++) {
      bf16x8 af[4], bf[4];
#pragma unroll
      for (int m = 0; m < 4; m++)
        af[m] = *(const bf16x8*)&Al[(wr * 64 + m * 16 + l15) * 64 + kk * 32 + lk * 8];
#pragma unroll
      for (int n = 0; n < 4; n++)
        bf[n] = *(const bf16x8*)&Bl[(wc * 64 + n * 16 + l15) * 64 + kk * 32 + lk * 8];
#pragma unroll
      for (int m = 0; m < 4; m++)
#pragma unroll
        for (int n = 0; n < 4; n++)
          acc[m][n] = __builtin_amdgcn_mfma_f32_16x16x32_bf16(af[m], bf[n], acc[m][n], 0, 0, 0);
    }
    __syncthreads();
  }

  if (MODE == 0) {
#pragma unroll
    for (int n = 0; n < 4; n++) {
      int c = n0 + wc * 64 + n * 16 + l15;
      int tsel = c >> 10, h = (c >> 6) & 15, d = c & 63;
      unsigned short* dst = (tsel == 0) ? qb : (tsel == 1 ? kb : vb);
      float sc = (tsel == 0) ? 0.125f : 1.0f;   // fold attn scale into Q
#pragma unroll
      for (int m = 0; m < 4; m++) {
#pragma unroll
        for (int r = 0; r < 4; r++) {
          int row = m0 + wr * 64 + m * 16 + lk * 4 + r;
          int b = row >> 11, nn = row & 2047;
          dst[(((size_t)(b * 16 + h)) * 2048 + nn) * 64 + d] = f2bf(acc[m][n][r] * sc);
        }
      }
    }
  } else {
#pragma unroll
    for (int n = 0; n < 4; n++) {
      int c = n0 + wc * 64 + n * 16 + l15;
      float bv = bias[c];
#pragma unroll
      for (int m = 0; m < 4; m++) {
#pragma unroll
        for (int r = 0; r < 4; r++) {
          int row = m0 + wr * 64 + m * 16 + lk * 4 + r;
          outp[(size_t)row * Nout + c] = acc[m][n][r] + bv;
        }
      }
    }
  }
}

// ---- Flash attention: block = 64 Q rows of one (b,h), KVBLK=128. ----
// 4 waves x 16 rows. K in Kl[128][72], Vt in Vl[64][136], P in Pl[64][136].
// 2 barriers/iter; next-tile global loads issued under compute (T14).
__global__ __launch_bounds__(256) void flash_kernel(
    const unsigned short* __restrict__ qb, const unsigned short* __restrict__ kb,
    const unsigned short* __restrict__ vtb, unsigned short* __restrict__ ob)
{
  __shared__ unsigned short Kl[KVB][72];    // [kv][d]   18432 B
  __shared__ unsigned short Vl[64][136];    // [d][kv]   17408 B
  __shared__ unsigned short Pl[64][136];    // [qrow][kv] 17408 B
  const int tid = threadIdx.x;
  const int w = tid >> 6;
  const int lane = tid & 63;
  const int l15 = lane & 15, lk = lane >> 4;
  const int q0 = blockIdx.x * 64;
  const int bh = blockIdx.y;
  const size_t base = (size_t)bh * N_ * D_;
  const unsigned short* Qg = qb + base;
  const unsigned short* Kg = kb + base;
  const unsigned short* Vtg = vtb + base;   // [d][n]

  // staging coords
  const int krow = tid >> 3, kc = (tid & 7) * 8;     // K: 4 issues of 32 rows
  const int vrow = tid >> 4, vc = (tid & 15) * 8;    // Vt: 4 issues of 16 rows

  // Q fragments (pre-scaled by 0.125 in the QKV-GEMM epilogue)
  bf16x8 qf[2];
#pragma unroll
  for (int kk = 0; kk < 2; kk++)
    qf[kk] = *(const bf16x8*)&Qg[(size_t)(q0 + w * 16 + l15) * 64 + kk * 32 + lk * 8];

  f32x4 acc_o[4];
#pragma unroll
  for (int i = 0; i < 4; i++) acc_o[i] = f32x4{0.f, 0.f, 0.f, 0.f};
  float mrow[4], lrow[4];
#pragma unroll
  for (int r = 0; r < 4; r++) { mrow[r] = -1e30f; lrow[r] = 0.f; }

  // prologue: load tile 0 into regs
  uint4 kreg[4], vreg[4];
#pragma unroll
  for (int i = 0; i < 4; i++)
    kreg[i] = *(const uint4*)&Kg[(size_t)(i * 32 + krow) * 64 + kc];
#pragma unroll
  for (int i = 0; i < 4; i++)
    vreg[i] = *(const uint4*)&Vtg[(size_t)(i * 16 + vrow) * N_ + vc];

  for (int kv0 = 0; kv0 < N_; kv0 += KVB) {
    // stage current tile regs -> LDS (vectorized b128)
#pragma unroll
    for (int i = 0; i < 4; i++) *(uint4*)&Kl[i * 32 + krow][kc] = kreg[i];
#pragma unroll
    for (int i = 0; i < 4; i++) *(uint4*)&Vl[i * 16 + vrow][vc] = vreg[i];
    __syncthreads();

    // issue next tile's global loads (hide HBM latency under compute)
    if (kv0 + KVB < N_) {
#pragma unroll
      for (int i = 0; i < 4; i++)
        kreg[i] = *(const uint4*)&Kg[(size_t)(kv0 + KVB + i * 32 + krow) * 64 + kc];
#pragma unroll
      for (int i = 0; i < 4; i++)
        vreg[i] = *(const uint4*)&Vtg[(size_t)(i * 16 + vrow) * N_ + kv0 + KVB + vc];
    }

    // S = Q K^T : 16 MFMA -> sa[8] (128 kv cols)
    f32x4 sa[8];
#pragma unroll
    for (int i = 0; i < 8; i++) sa[i] = f32x4{0.f, 0.f, 0.f, 0.f};
#pragma unroll
    for (int kk = 0; kk < 2; kk++) {
#pragma unroll
      for (int nf = 0; nf < 8; nf++) {
        bf16x8 b = *(const bf16x8*)&Kl[nf * 16 + l15][kk * 32 + lk * 8];
        sa[nf] = __builtin_amdgcn_mfma_f32_16x16x32_bf16(qf[kk], b, sa[nf], 0, 0, 0);
      }
    }

    // online softmax: one update per 128 kv
#pragma unroll
    for (int r = 0; r < 4; r++) {
      float s0 = sa[0][r], s1 = sa[1][r], s2 = sa[2][r], s3 = sa[3][r];
      float s4 = sa[4][r], s5 = sa[5][r], s6 = sa[6][r], s7 = sa[7][r];
      float mx = fmaxf(fmaxf(fmaxf(s0, s1), fmaxf(s2, s3)),
                       fmaxf(fmaxf(s4, s5), fmaxf(s6, s7)));
      mx = fmaxf(mx, __shfl_xor(mx, 1));
      mx = fmaxf(mx, __shfl_xor(mx, 2));
      mx = fmaxf(mx, __shfl_xor(mx, 4));
      mx = fmaxf(mx, __shfl_xor(mx, 8));
      float mnew = fmaxf(mrow[r], mx);
      float corr = __expf(mrow[r] - mnew);
      float p0 = __expf(s0 - mnew), p1 = __expf(s1 - mnew);
      float p2 = __expf(s2 - mnew), p3 = __expf(s3 - mnew);
      float p4 = __expf(s4 - mnew), p5 = __expf(s5 - mnew);
      float p6 = __expf(s6 - mnew), p7 = __expf(s7 - mnew);
      float rs = ((p0 + p1) + (p2 + p3)) + ((p4 + p5) + (p6 + p7));
      rs += __shfl_xor(rs, 1);
      rs += __shfl_xor(rs, 2);
      rs += __shfl_xor(rs, 4);
      rs += __shfl_xor(rs, 8);
      lrow[r] = lrow[r] * corr + rs;
      mrow[r] = mnew;
#pragma unroll
      for (int nf = 0; nf < 4; nf++) acc_o[nf][r] *= corr;
      int prow = w * 16 + lk * 4 + r;
      Pl[prow][0   + l15] = f2bf(p0);
      Pl[prow][16  + l15] = f2bf(p1);
      Pl[prow][32  + l15] = f2bf(p2);
      Pl[prow][48  + l15] = f2bf(p3);
      Pl[prow][64  + l15] = f2bf(p4);
      Pl[prow][80  + l15] = f2bf(p5);
      Pl[prow][96  + l15] = f2bf(p6);
      Pl[prow][112 + l15] = f2bf(p7);
    }
    // no barrier: each wave reads only its OWN Pl rows (in-wave lgkmcnt ordering)

    // O += P V : 16 MFMA
#pragma unroll
    for (int kk = 0; kk < 4; kk++) {
      bf16x8 a = *(const bf16x8*)&Pl[w * 16 + l15][kk * 32 + lk * 8];
#pragma unroll
      for (int nf = 0; nf < 4; nf++) {
        bf16x8 b = *(const bf16x8*)&Vl[nf * 16 + l15][kk * 32 + lk * 8];
        acc_o[nf] = __builtin_amdgcn_mfma_f32_16x16x32_bf16(a, b, acc_o[nf], 0, 0, 0);
      }
    }
    __syncthreads();   // all waves done reading Kl/Vl before next stage overwrite
  }

  // epilogue: O /= l ; write o as [B,N,H,D] (== [B,N,C])
  const int b = bh >> 4, h = bh & 15;
#pragma unroll
  for (int r = 0; r < 4; r++) {
    float inv = 1.0f / lrow[r];
    int n = q0 + w * 16 + lk * 4 + r;
    size_t obase = (((size_t)b * N_ + n) * H_ + h) * D_;
#pragma unroll
    for (int nf = 0; nf < 4; nf++)
      ob[obase + nf * 16 + l15] = f2bf(acc_o[nf][r] * inv);
  }
}

extern "C" void kernel_launch(void* const* d_in, const int* in_sizes, int n_in,
                              void* d_out, int out_size, void* d_ws, size_t ws_size,
                              hipStream_t stream) {
  const float* x      = (const float*)d_in[0];
  const float* w_qkv  = (const float*)d_in[1];
  const float* w_proj = (const float*)d_in[2];
  const float* b_proj = (const float*)d_in[3];
  float* out = (float*)d_out;

  const size_t qsz = (size_t)B_ * H_ * N_ * D_;          // 8388608 elems
  unsigned short* qb     = (unsigned short*)d_ws;
  unsigned short* kb     = qb + qsz;
  unsigned short* vb     = kb + qsz;
  unsigned short* vtb    = vb + qsz;                      // V transposed [bh][d][n]
  unsigned short* xbf    = vtb + qsz;                     // x as bf16; dead after qkv gemm
  unsigned short* ob     = xbf;                           // alias
  unsigned short* wqkv_t = xbf + qsz;                     // [3072][1024] bf16
  unsigned short* wproj_t= wqkv_t + (size_t)3072 * 1024;  // [1024][1024] bf16

  cvt_bf16_kernel<<<4096, 256, 0, stream>>>(x, xbf);
  transpose_cvt_kernel<<<dim3(3072 / 32, 1024 / 32), 256, 0, stream>>>(w_qkv, wqkv_t, 1024, 3072);
  transpose_cvt_kernel<<<dim3(1024 / 32, 1024 / 32), 256, 0, stream>>>(w_proj, wproj_t, 1024, 1024);

  // 1) qkv = x @ w_qkv -> q(scaled)/k/v [B,H,N,D]
  gemm128_kernel<0><<<dim3(3072 / 128, 8192 / 128), 256, 0, stream>>>(
      xbf, wqkv_t, nullptr, qb, kb, vb, nullptr, 8192, 1024, 3072);

  // 1b) vb -> vtb [bh][d][n]
  transpose_v_kernel<<<dim3(N_ / 64, B_ * H_), 256, 0, stream>>>(vb, vtb);

  // 2) flash attention
  flash_kernel<<<dim3(N_ / 64, B_ * H_), 256, 0, stream>>>(qb, kb, vtb, ob);

  // 3) out = o @ w_proj + b_proj
  gemm128_kernel<1><<<dim3(1024 / 128, 8192 / 128), 256, 0, stream>>>(
      ob, wproj_t, b_proj, nullptr, nullptr, nullptr, out, 8192, 1024, 1024);
}

// Round 5
// 437.469 us; speedup vs baseline: 1.5326x; 1.0045x over previous
//
#include <hip/hip_runtime.h>
#include <hip/hip_bf16.h>

// Fused attention forward: B=4, N=2048, C=1024, H=16, D=64.
// Round 4: fix flash scratch-spill (launch_bounds(256,2) -> VGPR cap 256),
// fold log2e into Q scale + exp2, setprio around MFMA clusters.
// GEMMs / preps unchanged from round 3.

#define B_ 4
#define N_ 2048
#define C_ 1024
#define H_ 16
#define D_ 64
#define KVB 128

typedef __attribute__((ext_vector_type(8))) __bf16 bf16x8;
typedef __attribute__((ext_vector_type(4))) float f32x4;
typedef unsigned int u32;

__device__ inline unsigned short f2bf(float f) {
  unsigned u = __float_as_uint(f);
  u += 0x7FFF + ((u >> 16) & 1);   // round-to-nearest-even
  return (unsigned short)(u >> 16);
}

__device__ __forceinline__ void gld16(const void* g, void* l) {
  __builtin_amdgcn_global_load_lds(
      (const __attribute__((address_space(1))) u32*)g,
      (__attribute__((address_space(3))) u32*)l, 16, 0, 0);
}

// ---- prep: fp32 -> bf16, same layout ----
__global__ __launch_bounds__(256) void cvt_bf16_kernel(
    const float* __restrict__ in, unsigned short* __restrict__ out) {
  int i = (blockIdx.x * 256 + threadIdx.x) * 8;
  float4 f0 = *(const float4*)&in[i];
  float4 f1 = *(const float4*)&in[i + 4];
  ushort4 h0, h1;
  h0.x = f2bf(f0.x); h0.y = f2bf(f0.y); h0.z = f2bf(f0.z); h0.w = f2bf(f0.w);
  h1.x = f2bf(f1.x); h1.y = f2bf(f1.y); h1.z = f2bf(f1.z); h1.w = f2bf(f1.w);
  *(ushort4*)&out[i] = h0;
  *(ushort4*)&out[i + 4] = h1;
}

// ---- prep: W[K][Nn] fp32 -> Wt[Nn][K] bf16 (32x32 tiles) ----
__global__ __launch_bounds__(256) void transpose_cvt_kernel(
    const float* __restrict__ in, unsigned short* __restrict__ out,
    int K, int Nn) {
  __shared__ float tile[32][33];
  const int t = threadIdx.x;
  const int k0 = blockIdx.y * 32, n0 = blockIdx.x * 32;
  {
    int r = t >> 3, c = (t & 7) * 4;
    float4 f = *(const float4*)&in[(size_t)(k0 + r) * Nn + n0 + c];
    tile[r][c + 0] = f.x; tile[r][c + 1] = f.y;
    tile[r][c + 2] = f.z; tile[r][c + 3] = f.w;
  }
  __syncthreads();
  {
    int nr = t >> 3, kc = (t & 7) * 4;
    ushort4 h;
    h.x = f2bf(tile[kc + 0][nr]);
    h.y = f2bf(tile[kc + 1][nr]);
    h.z = f2bf(tile[kc + 2][nr]);
    h.w = f2bf(tile[kc + 3][nr]);
    *(ushort4*)&out[(size_t)(n0 + nr) * K + k0 + kc] = h;
  }
}

// ---- prep: vb [bh][n][d] bf16 -> vtb [bh][d][n] bf16 (64x64 tiles) ----
__global__ __launch_bounds__(256) void transpose_v_kernel(
    const unsigned short* __restrict__ vb, unsigned short* __restrict__ vtb) {
  __shared__ u32 tile[64][65];
  const int tid = threadIdx.x;
  const int n0 = blockIdx.x * 64;
  const int bh = blockIdx.y;
  const size_t base = (size_t)bh * N_ * D_;
#pragma unroll
  for (int i = 0; i < 2; i++) {
    int id = i * 256 + tid;
    int row = id >> 3, c8 = id & 7;
    uint4 v = *(const uint4*)&vb[base + (size_t)(n0 + row) * D_ + c8 * 8];
    const unsigned short* pv = (const unsigned short*)&v;
#pragma unroll
    for (int j = 0; j < 8; j++) tile[row][c8 * 8 + j] = pv[j];
  }
  __syncthreads();
#pragma unroll
  for (int i = 0; i < 2; i++) {
    int id = i * 256 + tid;
    int d = id >> 3, nc = id & 7;
    uint4 o;
    unsigned short* po = (unsigned short*)&o;
#pragma unroll
    for (int j = 0; j < 8; j++) po[j] = (unsigned short)tile[nc * 8 + j][d];
    *(uint4*)&vtb[base + (size_t)d * N_ + n0 + nc * 8] = o;
  }
}

// ---- m97-class GEMM: C[M,Nout] = A[M,K] @ Bt[Nout,K]^T ----
// MODE 0: scatter bf16 to q/k/v [B,H,N,D]; q pre-scaled by 0.125*log2(e).
// MODE 1: fp32 out = acc + bias.
template<int MODE>
__global__ __launch_bounds__(256) void gemm128_kernel(
    const unsigned short* __restrict__ A, const unsigned short* __restrict__ Bt,
    const float* __restrict__ bias,
    unsigned short* __restrict__ qb, unsigned short* __restrict__ kb,
    unsigned short* __restrict__ vb, float* __restrict__ outp,
    int M, int K, int Nout)
{
  __shared__ unsigned short Al[128 * 64];
  __shared__ unsigned short Bl[128 * 64];
  const int tid = threadIdx.x;
  const int w = tid >> 6, lane = tid & 63;
  const int l15 = lane & 15, lk = lane >> 4;
  const int wr = w >> 1, wc = w & 1;
  const int n0 = blockIdx.x * 128, m0 = blockIdx.y * 128;
  const int srow = tid >> 3;
  const int scol = (tid & 7) * 8;

  f32x4 acc[4][4];
#pragma unroll
  for (int m = 0; m < 4; m++)
#pragma unroll
    for (int n = 0; n < 4; n++) acc[m][n] = f32x4{0.f, 0.f, 0.f, 0.f};

  for (int kt = 0; kt < K; kt += 64) {
#pragma unroll
    for (int i = 0; i < 4; i++)
      gld16(&A[(size_t)(m0 + i * 32 + srow) * K + kt + scol],
            &Al[i * 2048 + w * 512]);
#pragma unroll
    for (int i = 0; i < 4; i++)
      gld16(&Bt[(size_t)(n0 + i * 32 + srow) * K + kt + scol],
            &Bl[i * 2048 + w * 512]);
    __syncthreads();

#pragma unroll
    for (int kk = 0; kk < 2; kk++) {
      bf16x8 af[4], bf[4];
#pragma unroll
      for (int m = 0; m < 4; m++)
        af[m] = *(const bf16x8*)&Al[(wr * 64 + m * 16 + l15) * 64 + kk * 32 + lk * 8];
#pragma unroll
      for (int n = 0; n < 4; n++)
        bf[n] = *(const bf16x8*)&Bl[(wc * 64 + n * 16 + l15) * 64 + kk * 32 + lk * 8];
#pragma unroll
      for (int m = 0; m < 4; m++)
#pragma unroll
        for (int n = 0; n < 4; n++)
          acc[m][n] = __builtin_amdgcn_mfma_f32_16x16x32_bf16(af[m], bf[n], acc[m][n], 0, 0, 0);
    }
    __syncthreads();
  }

  if (MODE == 0) {
#pragma unroll
    for (int n = 0; n < 4; n++) {
      int c = n0 + wc * 64 + n * 16 + l15;
      int tsel = c >> 10, h = (c >> 6) & 15, d = c & 63;
      unsigned short* dst = (tsel == 0) ? qb : (tsel == 1 ? kb : vb);
      // fold attn scale AND log2(e) into Q (softmax uses exp2)
      float sc = (tsel == 0) ? 0.125f * 1.44269504088896340736f : 1.0f;
#pragma unroll
      for (int m = 0; m < 4; m++) {
#pragma unroll
        for (int r = 0; r < 4; r++) {
          int row = m0 + wr * 64 + m * 16 + lk * 4 + r;
          int b = row >> 11, nn = row & 2047;
          dst[(((size_t)(b * 16 + h)) * 2048 + nn) * 64 + d] = f2bf(acc[m][n][r] * sc);
        }
      }
    }
  } else {
#pragma unroll
    for (int n = 0; n < 4; n++) {
      int c = n0 + wc * 64 + n * 16 + l15;
      float bv = bias[c];
#pragma unroll
      for (int m = 0; m < 4; m++) {
#pragma unroll
        for (int r = 0; r < 4; r++) {
          int row = m0 + wr * 64 + m * 16 + lk * 4 + r;
          outp[(size_t)row * Nout + c] = acc[m][n][r] + bv;
        }
      }
    }
  }
}

// ---- Flash attention: block = 64 Q rows of one (b,h), KVBLK=128. ----
// __launch_bounds__(256,2): VGPR cap 256 -> no scratch spill (round-3 bug:
// default heuristic capped at 68 VGPR and spilled kreg/vreg -> 1 GB/dispatch).
__global__ __launch_bounds__(256, 2) void flash_kernel(
    const unsigned short* __restrict__ qb, const unsigned short* __restrict__ kb,
    const unsigned short* __restrict__ vtb, unsigned short* __restrict__ ob)
{
  __shared__ unsigned short Kl[KVB][72];    // [kv][d]
  __shared__ unsigned short Vl[64][136];    // [d][kv]
  __shared__ unsigned short Pl[64][136];    // [qrow][kv]
  const int tid = threadIdx.x;
  const int w = tid >> 6;
  const int lane = tid & 63;
  const int l15 = lane & 15, lk = lane >> 4;
  const int q0 = blockIdx.x * 64;
  const int bh = blockIdx.y;
  const size_t base = (size_t)bh * N_ * D_;
  const unsigned short* Qg = qb + base;
  const unsigned short* Kg = kb + base;
  const unsigned short* Vtg = vtb + base;   // [d][n]

  const int krow = tid >> 3, kc = (tid & 7) * 8;
  const int vrow = tid >> 4, vc = (tid & 15) * 8;

  bf16x8 qf[2];
#pragma unroll
  for (int kk = 0; kk < 2; kk++)
    qf[kk] = *(const bf16x8*)&Qg[(size_t)(q0 + w * 16 + l15) * 64 + kk * 32 + lk * 8];

  f32x4 acc_o[4];
#pragma unroll
  for (int i = 0; i < 4; i++) acc_o[i] = f32x4{0.f, 0.f, 0.f, 0.f};
  float mrow[4], lrow[4];
#pragma unroll
  for (int r = 0; r < 4; r++) { mrow[r] = -1e30f; lrow[r] = 0.f; }

  uint4 kreg[4], vreg[4];
#pragma unroll
  for (int i = 0; i < 4; i++)
    kreg[i] = *(const uint4*)&Kg[(size_t)(i * 32 + krow) * 64 + kc];
#pragma unroll
  for (int i = 0; i < 4; i++)
    vreg[i] = *(const uint4*)&Vtg[(size_t)(i * 16 + vrow) * N_ + vc];

  for (int kv0 = 0; kv0 < N_; kv0 += KVB) {
#pragma unroll
    for (int i = 0; i < 4; i++) *(uint4*)&Kl[i * 32 + krow][kc] = kreg[i];
#pragma unroll
    for (int i = 0; i < 4; i++) *(uint4*)&Vl[i * 16 + vrow][vc] = vreg[i];
    __syncthreads();

    // issue next tile's global loads (hide HBM latency under compute)
    if (kv0 + KVB < N_) {
#pragma unroll
      for (int i = 0; i < 4; i++)
        kreg[i] = *(const uint4*)&Kg[(size_t)(kv0 + KVB + i * 32 + krow) * 64 + kc];
#pragma unroll
      for (int i = 0; i < 4; i++)
        vreg[i] = *(const uint4*)&Vtg[(size_t)(i * 16 + vrow) * N_ + kv0 + KVB + vc];
    }

    // S = Q K^T : 16 MFMA -> sa[8] (128 kv cols); S is in log2-units
    f32x4 sa[8];
#pragma unroll
    for (int i = 0; i < 8; i++) sa[i] = f32x4{0.f, 0.f, 0.f, 0.f};
    __builtin_amdgcn_s_setprio(1);
#pragma unroll
    for (int kk = 0; kk < 2; kk++) {
#pragma unroll
      for (int nf = 0; nf < 8; nf++) {
        bf16x8 b = *(const bf16x8*)&Kl[nf * 16 + l15][kk * 32 + lk * 8];
        sa[nf] = __builtin_amdgcn_mfma_f32_16x16x32_bf16(qf[kk], b, sa[nf], 0, 0, 0);
      }
    }
    __builtin_amdgcn_s_setprio(0);

    // online softmax (base-2): one update per 128 kv
#pragma unroll
    for (int r = 0; r < 4; r++) {
      float s0 = sa[0][r], s1 = sa[1][r], s2 = sa[2][r], s3 = sa[3][r];
      float s4 = sa[4][r], s5 = sa[5][r], s6 = sa[6][r], s7 = sa[7][r];
      float mx = fmaxf(fmaxf(fmaxf(s0, s1), fmaxf(s2, s3)),
                       fmaxf(fmaxf(s4, s5), fmaxf(s6, s7)));
      mx = fmaxf(mx, __shfl_xor(mx, 1));
      mx = fmaxf(mx, __shfl_xor(mx, 2));
      mx = fmaxf(mx, __shfl_xor(mx, 4));
      mx = fmaxf(mx, __shfl_xor(mx, 8));
      float mnew = fmaxf(mrow[r], mx);
      float corr = __builtin_amdgcn_exp2f(mrow[r] - mnew);
      float p0 = __builtin_amdgcn_exp2f(s0 - mnew);
      float p1 = __builtin_amdgcn_exp2f(s1 - mnew);
      float p2 = __builtin_amdgcn_exp2f(s2 - mnew);
      float p3 = __builtin_amdgcn_exp2f(s3 - mnew);
      float p4 = __builtin_amdgcn_exp2f(s4 - mnew);
      float p5 = __builtin_amdgcn_exp2f(s5 - mnew);
      float p6 = __builtin_amdgcn_exp2f(s6 - mnew);
      float p7 = __builtin_amdgcn_exp2f(s7 - mnew);
      float rs = ((p0 + p1) + (p2 + p3)) + ((p4 + p5) + (p6 + p7));
      rs += __shfl_xor(rs, 1);
      rs += __shfl_xor(rs, 2);
      rs += __shfl_xor(rs, 4);
      rs += __shfl_xor(rs, 8);
      lrow[r] = lrow[r] * corr + rs;
      mrow[r] = mnew;
#pragma unroll
      for (int nf = 0; nf < 4; nf++) acc_o[nf][r] *= corr;
      int prow = w * 16 + lk * 4 + r;
      Pl[prow][0   + l15] = f2bf(p0);
      Pl[prow][16  + l15] = f2bf(p1);
      Pl[prow][32  + l15] = f2bf(p2);
      Pl[prow][48  + l15] = f2bf(p3);
      Pl[prow][64  + l15] = f2bf(p4);
      Pl[prow][80  + l15] = f2bf(p5);
      Pl[prow][96  + l15] = f2bf(p6);
      Pl[prow][112 + l15] = f2bf(p7);
    }
    // no barrier: each wave reads only its OWN Pl rows (in-wave LDS ordering)

    // O += P V : 16 MFMA
    __builtin_amdgcn_s_setprio(1);
#pragma unroll
    for (int kk = 0; kk < 4; kk++) {
      bf16x8 a = *(const bf16x8*)&Pl[w * 16 + l15][kk * 32 + lk * 8];
#pragma unroll
      for (int nf = 0; nf < 4; nf++) {
        bf16x8 b = *(const bf16x8*)&Vl[nf * 16 + l15][kk * 32 + lk * 8];
        acc_o[nf] = __builtin_amdgcn_mfma_f32_16x16x32_bf16(a, b, acc_o[nf], 0, 0, 0);
      }
    }
    __builtin_amdgcn_s_setprio(0);
    __syncthreads();   // all waves done reading Kl/Vl before next stage overwrite
  }

  const int b = bh >> 4, h = bh & 15;
#pragma unroll
  for (int r = 0; r < 4; r++) {
    float inv = 1.0f / lrow[r];
    int n = q0 + w * 16 + lk * 4 + r;
    size_t obase = (((size_t)b * N_ + n) * H_ + h) * D_;
#pragma unroll
    for (int nf = 0; nf < 4; nf++)
      ob[obase + nf * 16 + l15] = f2bf(acc_o[nf][r] * inv);
  }
}

extern "C" void kernel_launch(void* const* d_in, const int* in_sizes, int n_in,
                              void* d_out, int out_size, void* d_ws, size_t ws_size,
                              hipStream_t stream) {
  const float* x      = (const float*)d_in[0];
  const float* w_qkv  = (const float*)d_in[1];
  const float* w_proj = (const float*)d_in[2];
  const float* b_proj = (const float*)d_in[3];
  float* out = (float*)d_out;

  const size_t qsz = (size_t)B_ * H_ * N_ * D_;
  unsigned short* qb     = (unsigned short*)d_ws;
  unsigned short* kb     = qb + qsz;
  unsigned short* vb     = kb + qsz;
  unsigned short* vtb    = vb + qsz;
  unsigned short* xbf    = vtb + qsz;
  unsigned short* ob     = xbf;                           // alias: x dead after qkv
  unsigned short* wqkv_t = xbf + qsz;
  unsigned short* wproj_t= wqkv_t + (size_t)3072 * 1024;

  cvt_bf16_kernel<<<4096, 256, 0, stream>>>(x, xbf);
  transpose_cvt_kernel<<<dim3(3072 / 32, 1024 / 32), 256, 0, stream>>>(w_qkv, wqkv_t, 1024, 3072);
  transpose_cvt_kernel<<<dim3(1024 / 32, 1024 / 32), 256, 0, stream>>>(w_proj, wproj_t, 1024, 1024);

  gemm128_kernel<0><<<dim3(3072 / 128, 8192 / 128), 256, 0, stream>>>(
      xbf, wqkv_t, nullptr, qb, kb, vb, nullptr, 8192, 1024, 3072);

  transpose_v_kernel<<<dim3(N_ / 64, B_ * H_), 256, 0, stream>>>(vb, vtb);

  flash_kernel<<<dim3(N_ / 64, B_ * H_), 256, 0, stream>>>(qb, kb, vtb, ob);

  gemm128_kernel<1><<<dim3(1024 / 128, 8192 / 128), 256, 0, stream>>>(
      ob, wproj_t, b_proj, nullptr, nullptr, nullptr, out, 8192, 1024, 1024);
}

// Round 6
// 436.723 us; speedup vs baseline: 1.5352x; 1.0017x over previous
//
#include <hip/hip_runtime.h>
#include <hip/hip_bf16.h>

// Fused attention forward: B=4, N=2048, C=1024, H=16, D=64.
// Round 5: kill flash scratch-spill for real. launch_bounds(256,2) was a no-op
// (sets only the waves/EU MIN = usage cap 256, already satisfied at 68; the
// allocator's occupancy TARGET stayed ~8 waves/EU -> 64-reg budget -> spill).
// amdgpu_waves_per_eu(2,3) lowers the TARGET: budget 512/3=170 >= ~120 live.
// Everything else identical to round 4.

#define B_ 4
#define N_ 2048
#define C_ 1024
#define H_ 16
#define D_ 64
#define KVB 128

typedef __attribute__((ext_vector_type(8))) __bf16 bf16x8;
typedef __attribute__((ext_vector_type(4))) float f32x4;
typedef unsigned int u32;

__device__ inline unsigned short f2bf(float f) {
  unsigned u = __float_as_uint(f);
  u += 0x7FFF + ((u >> 16) & 1);   // round-to-nearest-even
  return (unsigned short)(u >> 16);
}

__device__ __forceinline__ void gld16(const void* g, void* l) {
  __builtin_amdgcn_global_load_lds(
      (const __attribute__((address_space(1))) u32*)g,
      (__attribute__((address_space(3))) u32*)l, 16, 0, 0);
}

// ---- prep: fp32 -> bf16, same layout ----
__global__ __launch_bounds__(256) void cvt_bf16_kernel(
    const float* __restrict__ in, unsigned short* __restrict__ out) {
  int i = (blockIdx.x * 256 + threadIdx.x) * 8;
  float4 f0 = *(const float4*)&in[i];
  float4 f1 = *(const float4*)&in[i + 4];
  ushort4 h0, h1;
  h0.x = f2bf(f0.x); h0.y = f2bf(f0.y); h0.z = f2bf(f0.z); h0.w = f2bf(f0.w);
  h1.x = f2bf(f1.x); h1.y = f2bf(f1.y); h1.z = f2bf(f1.z); h1.w = f2bf(f1.w);
  *(ushort4*)&out[i] = h0;
  *(ushort4*)&out[i + 4] = h1;
}

// ---- prep: W[K][Nn] fp32 -> Wt[Nn][K] bf16 (32x32 tiles) ----
__global__ __launch_bounds__(256) void transpose_cvt_kernel(
    const float* __restrict__ in, unsigned short* __restrict__ out,
    int K, int Nn) {
  __shared__ float tile[32][33];
  const int t = threadIdx.x;
  const int k0 = blockIdx.y * 32, n0 = blockIdx.x * 32;
  {
    int r = t >> 3, c = (t & 7) * 4;
    float4 f = *(const float4*)&in[(size_t)(k0 + r) * Nn + n0 + c];
    tile[r][c + 0] = f.x; tile[r][c + 1] = f.y;
    tile[r][c + 2] = f.z; tile[r][c + 3] = f.w;
  }
  __syncthreads();
  {
    int nr = t >> 3, kc = (t & 7) * 4;
    ushort4 h;
    h.x = f2bf(tile[kc + 0][nr]);
    h.y = f2bf(tile[kc + 1][nr]);
    h.z = f2bf(tile[kc + 2][nr]);
    h.w = f2bf(tile[kc + 3][nr]);
    *(ushort4*)&out[(size_t)(n0 + nr) * K + k0 + kc] = h;
  }
}

// ---- prep: vb [bh][n][d] bf16 -> vtb [bh][d][n] bf16 (64x64 tiles) ----
__global__ __launch_bounds__(256) void transpose_v_kernel(
    const unsigned short* __restrict__ vb, unsigned short* __restrict__ vtb) {
  __shared__ u32 tile[64][65];
  const int tid = threadIdx.x;
  const int n0 = blockIdx.x * 64;
  const int bh = blockIdx.y;
  const size_t base = (size_t)bh * N_ * D_;
#pragma unroll
  for (int i = 0; i < 2; i++) {
    int id = i * 256 + tid;
    int row = id >> 3, c8 = id & 7;
    uint4 v = *(const uint4*)&vb[base + (size_t)(n0 + row) * D_ + c8 * 8];
    const unsigned short* pv = (const unsigned short*)&v;
#pragma unroll
    for (int j = 0; j < 8; j++) tile[row][c8 * 8 + j] = pv[j];
  }
  __syncthreads();
#pragma unroll
  for (int i = 0; i < 2; i++) {
    int id = i * 256 + tid;
    int d = id >> 3, nc = id & 7;
    uint4 o;
    unsigned short* po = (unsigned short*)&o;
#pragma unroll
    for (int j = 0; j < 8; j++) po[j] = (unsigned short)tile[nc * 8 + j][d];
    *(uint4*)&vtb[base + (size_t)d * N_ + n0 + nc * 8] = o;
  }
}

// ---- m97-class GEMM: C[M,Nout] = A[M,K] @ Bt[Nout,K]^T ----
// MODE 0: scatter bf16 to q/k/v [B,H,N,D]; q pre-scaled by 0.125*log2(e).
// MODE 1: fp32 out = acc + bias.
template<int MODE>
__global__ __launch_bounds__(256) void gemm128_kernel(
    const unsigned short* __restrict__ A, const unsigned short* __restrict__ Bt,
    const float* __restrict__ bias,
    unsigned short* __restrict__ qb, unsigned short* __restrict__ kb,
    unsigned short* __restrict__ vb, float* __restrict__ outp,
    int M, int K, int Nout)
{
  __shared__ unsigned short Al[128 * 64];
  __shared__ unsigned short Bl[128 * 64];
  const int tid = threadIdx.x;
  const int w = tid >> 6, lane = tid & 63;
  const int l15 = lane & 15, lk = lane >> 4;
  const int wr = w >> 1, wc = w & 1;
  const int n0 = blockIdx.x * 128, m0 = blockIdx.y * 128;
  const int srow = tid >> 3;
  const int scol = (tid & 7) * 8;

  f32x4 acc[4][4];
#pragma unroll
  for (int m = 0; m < 4; m++)
#pragma unroll
    for (int n = 0; n < 4; n++) acc[m][n] = f32x4{0.f, 0.f, 0.f, 0.f};

  for (int kt = 0; kt < K; kt += 64) {
#pragma unroll
    for (int i = 0; i < 4; i++)
      gld16(&A[(size_t)(m0 + i * 32 + srow) * K + kt + scol],
            &Al[i * 2048 + w * 512]);
#pragma unroll
    for (int i = 0; i < 4; i++)
      gld16(&Bt[(size_t)(n0 + i * 32 + srow) * K + kt + scol],
            &Bl[i * 2048 + w * 512]);
    __syncthreads();

#pragma unroll
    for (int kk = 0; kk < 2; kk++) {
      bf16x8 af[4], bf[4];
#pragma unroll
      for (int m = 0; m < 4; m++)
        af[m] = *(const bf16x8*)&Al[(wr * 64 + m * 16 + l15) * 64 + kk * 32 + lk * 8];
#pragma unroll
      for (int n = 0; n < 4; n++)
        bf[n] = *(const bf16x8*)&Bl[(wc * 64 + n * 16 + l15) * 64 + kk * 32 + lk * 8];
#pragma unroll
      for (int m = 0; m < 4; m++)
#pragma unroll
        for (int n = 0; n < 4; n++)
          acc[m][n] = __builtin_amdgcn_mfma_f32_16x16x32_bf16(af[m], bf[n], acc[m][n], 0, 0, 0);
    }
    __syncthreads();
  }

  if (MODE == 0) {
#pragma unroll
    for (int n = 0; n < 4; n++) {
      int c = n0 + wc * 64 + n * 16 + l15;
      int tsel = c >> 10, h = (c >> 6) & 15, d = c & 63;
      unsigned short* dst = (tsel == 0) ? qb : (tsel == 1 ? kb : vb);
      float sc = (tsel == 0) ? 0.125f * 1.44269504088896340736f : 1.0f;
#pragma unroll
      for (int m = 0; m < 4; m++) {
#pragma unroll
        for (int r = 0; r < 4; r++) {
          int row = m0 + wr * 64 + m * 16 + lk * 4 + r;
          int b = row >> 11, nn = row & 2047;
          dst[(((size_t)(b * 16 + h)) * 2048 + nn) * 64 + d] = f2bf(acc[m][n][r] * sc);
        }
      }
    }
  } else {
#pragma unroll
    for (int n = 0; n < 4; n++) {
      int c = n0 + wc * 64 + n * 16 + l15;
      float bv = bias[c];
#pragma unroll
      for (int m = 0; m < 4; m++) {
#pragma unroll
        for (int r = 0; r < 4; r++) {
          int row = m0 + wr * 64 + m * 16 + lk * 4 + r;
          outp[(size_t)row * Nout + c] = acc[m][n][r] + bv;
        }
      }
    }
  }
}

// ---- Flash attention: block = 64 Q rows of one (b,h), KVBLK=128. ----
// amdgpu_waves_per_eu(2,3): allocator budget 512/3=170 VGPR (LDS caps us at
// 3 blocks/CU anyway) -> the ~120 live regs fit, no scratch spill.
__global__ __attribute__((amdgpu_waves_per_eu(2, 3))) __launch_bounds__(256)
void flash_kernel(
    const unsigned short* __restrict__ qb, const unsigned short* __restrict__ kb,
    const unsigned short* __restrict__ vtb, unsigned short* __restrict__ ob)
{
  __shared__ unsigned short Kl[KVB][72];    // [kv][d]
  __shared__ unsigned short Vl[64][136];    // [d][kv]
  __shared__ unsigned short Pl[64][136];    // [qrow][kv]
  const int tid = threadIdx.x;
  const int w = tid >> 6;
  const int lane = tid & 63;
  const int l15 = lane & 15, lk = lane >> 4;
  const int q0 = blockIdx.x * 64;
  const int bh = blockIdx.y;
  const size_t base = (size_t)bh * N_ * D_;
  const unsigned short* Qg = qb + base;
  const unsigned short* Kg = kb + base;
  const unsigned short* Vtg = vtb + base;   // [d][n]

  const int krow = tid >> 3, kc = (tid & 7) * 8;
  const int vrow = tid >> 4, vc = (tid & 15) * 8;

  bf16x8 qf[2];
#pragma unroll
  for (int kk = 0; kk < 2; kk++)
    qf[kk] = *(const bf16x8*)&Qg[(size_t)(q0 + w * 16 + l15) * 64 + kk * 32 + lk * 8];

  f32x4 acc_o[4];
#pragma unroll
  for (int i = 0; i < 4; i++) acc_o[i] = f32x4{0.f, 0.f, 0.f, 0.f};
  float mrow[4], lrow[4];
#pragma unroll
  for (int r = 0; r < 4; r++) { mrow[r] = -1e30f; lrow[r] = 0.f; }

  uint4 kreg[4], vreg[4];
#pragma unroll
  for (int i = 0; i < 4; i++)
    kreg[i] = *(const uint4*)&Kg[(size_t)(i * 32 + krow) * 64 + kc];
#pragma unroll
  for (int i = 0; i < 4; i++)
    vreg[i] = *(const uint4*)&Vtg[(size_t)(i * 16 + vrow) * N_ + vc];

  for (int kv0 = 0; kv0 < N_; kv0 += KVB) {
#pragma unroll
    for (int i = 0; i < 4; i++) *(uint4*)&Kl[i * 32 + krow][kc] = kreg[i];
#pragma unroll
    for (int i = 0; i < 4; i++) *(uint4*)&Vl[i * 16 + vrow][vc] = vreg[i];
    __syncthreads();

    // issue next tile's global loads (hide HBM latency under compute)
    if (kv0 + KVB < N_) {
#pragma unroll
      for (int i = 0; i < 4; i++)
        kreg[i] = *(const uint4*)&Kg[(size_t)(kv0 + KVB + i * 32 + krow) * 64 + kc];
#pragma unroll
      for (int i = 0; i < 4; i++)
        vreg[i] = *(const uint4*)&Vtg[(size_t)(i * 16 + vrow) * N_ + kv0 + KVB + vc];
    }

    // S = Q K^T : 16 MFMA -> sa[8] (128 kv cols); S is in log2-units
    f32x4 sa[8];
#pragma unroll
    for (int i = 0; i < 8; i++) sa[i] = f32x4{0.f, 0.f, 0.f, 0.f};
    __builtin_amdgcn_s_setprio(1);
#pragma unroll
    for (int kk = 0; kk < 2; kk++) {
#pragma unroll
      for (int nf = 0; nf < 8; nf++) {
        bf16x8 b = *(const bf16x8*)&Kl[nf * 16 + l15][kk * 32 + lk * 8];
        sa[nf] = __builtin_amdgcn_mfma_f32_16x16x32_bf16(qf[kk], b, sa[nf], 0, 0, 0);
      }
    }
    __builtin_amdgcn_s_setprio(0);

    // online softmax (base-2): one update per 128 kv
#pragma unroll
    for (int r = 0; r < 4; r++) {
      float s0 = sa[0][r], s1 = sa[1][r], s2 = sa[2][r], s3 = sa[3][r];
      float s4 = sa[4][r], s5 = sa[5][r], s6 = sa[6][r], s7 = sa[7][r];
      float mx = fmaxf(fmaxf(fmaxf(s0, s1), fmaxf(s2, s3)),
                       fmaxf(fmaxf(s4, s5), fmaxf(s6, s7)));
      mx = fmaxf(mx, __shfl_xor(mx, 1));
      mx = fmaxf(mx, __shfl_xor(mx, 2));
      mx = fmaxf(mx, __shfl_xor(mx, 4));
      mx = fmaxf(mx, __shfl_xor(mx, 8));
      float mnew = fmaxf(mrow[r], mx);
      float corr = __builtin_amdgcn_exp2f(mrow[r] - mnew);
      float p0 = __builtin_amdgcn_exp2f(s0 - mnew);
      float p1 = __builtin_amdgcn_exp2f(s1 - mnew);
      float p2 = __builtin_amdgcn_exp2f(s2 - mnew);
      float p3 = __builtin_amdgcn_exp2f(s3 - mnew);
      float p4 = __builtin_amdgcn_exp2f(s4 - mnew);
      float p5 = __builtin_amdgcn_exp2f(s5 - mnew);
      float p6 = __builtin_amdgcn_exp2f(s6 - mnew);
      float p7 = __builtin_amdgcn_exp2f(s7 - mnew);
      float rs = ((p0 + p1) + (p2 + p3)) + ((p4 + p5) + (p6 + p7));
      rs += __shfl_xor(rs, 1);
      rs += __shfl_xor(rs, 2);
      rs += __shfl_xor(rs, 4);
      rs += __shfl_xor(rs, 8);
      lrow[r] = lrow[r] * corr + rs;
      mrow[r] = mnew;
#pragma unroll
      for (int nf = 0; nf < 4; nf++) acc_o[nf][r] *= corr;
      int prow = w * 16 + lk * 4 + r;
      Pl[prow][0   + l15] = f2bf(p0);
      Pl[prow][16  + l15] = f2bf(p1);
      Pl[prow][32  + l15] = f2bf(p2);
      Pl[prow][48  + l15] = f2bf(p3);
      Pl[prow][64  + l15] = f2bf(p4);
      Pl[prow][80  + l15] = f2bf(p5);
      Pl[prow][96  + l15] = f2bf(p6);
      Pl[prow][112 + l15] = f2bf(p7);
    }
    // no barrier: each wave reads only its OWN Pl rows (in-wave LDS ordering)

    // O += P V : 16 MFMA
    __builtin_amdgcn_s_setprio(1);
#pragma unroll
    for (int kk = 0; kk < 4; kk++) {
      bf16x8 a = *(const bf16x8*)&Pl[w * 16 + l15][kk * 32 + lk * 8];
#pragma unroll
      for (int nf = 0; nf < 4; nf++) {
        bf16x8 b = *(const bf16x8*)&Vl[nf * 16 + l15][kk * 32 + lk * 8];
        acc_o[nf] = __builtin_amdgcn_mfma_f32_16x16x32_bf16(a, b, acc_o[nf], 0, 0, 0);
      }
    }
    __builtin_amdgcn_s_setprio(0);
    __syncthreads();   // all waves done reading Kl/Vl before next stage overwrite
  }

  const int b = bh >> 4, h = bh & 15;
#pragma unroll
  for (int r = 0; r < 4; r++) {
    float inv = 1.0f / lrow[r];
    int n = q0 + w * 16 + lk * 4 + r;
    size_t obase = (((size_t)b * N_ + n) * H_ + h) * D_;
#pragma unroll
    for (int nf = 0; nf < 4; nf++)
      ob[obase + nf * 16 + l15] = f2bf(acc_o[nf][r] * inv);
  }
}

extern "C" void kernel_launch(void* const* d_in, const int* in_sizes, int n_in,
                              void* d_out, int out_size, void* d_ws, size_t ws_size,
                              hipStream_t stream) {
  const float* x      = (const float*)d_in[0];
  const float* w_qkv  = (const float*)d_in[1];
  const float* w_proj = (const float*)d_in[2];
  const float* b_proj = (const float*)d_in[3];
  float* out = (float*)d_out;

  const size_t qsz = (size_t)B_ * H_ * N_ * D_;
  unsigned short* qb     = (unsigned short*)d_ws;
  unsigned short* kb     = qb + qsz;
  unsigned short* vb     = kb + qsz;
  unsigned short* vtb    = vb + qsz;
  unsigned short* xbf    = vtb + qsz;
  unsigned short* ob     = xbf;                           // alias: x dead after qkv
  unsigned short* wqkv_t = xbf + qsz;
  unsigned short* wproj_t= wqkv_t + (size_t)3072 * 1024;

  cvt_bf16_kernel<<<4096, 256, 0, stream>>>(x, xbf);
  transpose_cvt_kernel<<<dim3(3072 / 32, 1024 / 32), 256, 0, stream>>>(w_qkv, wqkv_t, 1024, 3072);
  transpose_cvt_kernel<<<dim3(1024 / 32, 1024 / 32), 256, 0, stream>>>(w_proj, wproj_t, 1024, 1024);

  gemm128_kernel<0><<<dim3(3072 / 128, 8192 / 128), 256, 0, stream>>>(
      xbf, wqkv_t, nullptr, qb, kb, vb, nullptr, 8192, 1024, 3072);

  transpose_v_kernel<<<dim3(N_ / 64, B_ * H_), 256, 0, stream>>>(vb, vtb);

  flash_kernel<<<dim3(N_ / 64, B_ * H_), 256, 0, stream>>>(qb, kb, vtb, ob);

  gemm128_kernel<1><<<dim3(1024 / 128, 8192 / 128), 256, 0, stream>>>(
      ob, wproj_t, b_proj, nullptr, nullptr, nullptr, out, 8192, 1024, 1024);
}

// Round 7
// 301.086 us; speedup vs baseline: 2.2268x; 1.4505x over previous
//
#include <hip/hip_runtime.h>
#include <hip/hip_bf16.h>

// Fused attention forward: B=4, N=2048, C=1024, H=16, D=64.
// Round 6: flash staging via global_load_lds (NO register prefetch -> the 32
// spilled VGPRs are gone structurally; rounds 4/5 attribute knobs were null).
// Linear K[128][64] / Vt[64][128] LDS tiles with both-sides XOR swizzle
// (source slot ^ (row&7), read col ^ (row&7)<<3) to kill the 16-way
// stride-128B/256B bank conflict. GEMMs / preps unchanged.

#define B_ 4
#define N_ 2048
#define C_ 1024
#define H_ 16
#define D_ 64
#define KVB 128

typedef __attribute__((ext_vector_type(8))) __bf16 bf16x8;
typedef __attribute__((ext_vector_type(4))) float f32x4;
typedef unsigned int u32;

__device__ inline unsigned short f2bf(float f) {
  unsigned u = __float_as_uint(f);
  u += 0x7FFF + ((u >> 16) & 1);   // round-to-nearest-even
  return (unsigned short)(u >> 16);
}

__device__ __forceinline__ void gld16(const void* g, void* l) {
  __builtin_amdgcn_global_load_lds(
      (const __attribute__((address_space(1))) u32*)g,
      (__attribute__((address_space(3))) u32*)l, 16, 0, 0);
}

// ---- prep: fp32 -> bf16, same layout ----
__global__ __launch_bounds__(256) void cvt_bf16_kernel(
    const float* __restrict__ in, unsigned short* __restrict__ out) {
  int i = (blockIdx.x * 256 + threadIdx.x) * 8;
  float4 f0 = *(const float4*)&in[i];
  float4 f1 = *(const float4*)&in[i + 4];
  ushort4 h0, h1;
  h0.x = f2bf(f0.x); h0.y = f2bf(f0.y); h0.z = f2bf(f0.z); h0.w = f2bf(f0.w);
  h1.x = f2bf(f1.x); h1.y = f2bf(f1.y); h1.z = f2bf(f1.z); h1.w = f2bf(f1.w);
  *(ushort4*)&out[i] = h0;
  *(ushort4*)&out[i + 4] = h1;
}

// ---- prep: W[K][Nn] fp32 -> Wt[Nn][K] bf16 (32x32 tiles) ----
__global__ __launch_bounds__(256) void transpose_cvt_kernel(
    const float* __restrict__ in, unsigned short* __restrict__ out,
    int K, int Nn) {
  __shared__ float tile[32][33];
  const int t = threadIdx.x;
  const int k0 = blockIdx.y * 32, n0 = blockIdx.x * 32;
  {
    int r = t >> 3, c = (t & 7) * 4;
    float4 f = *(const float4*)&in[(size_t)(k0 + r) * Nn + n0 + c];
    tile[r][c + 0] = f.x; tile[r][c + 1] = f.y;
    tile[r][c + 2] = f.z; tile[r][c + 3] = f.w;
  }
  __syncthreads();
  {
    int nr = t >> 3, kc = (t & 7) * 4;
    ushort4 h;
    h.x = f2bf(tile[kc + 0][nr]);
    h.y = f2bf(tile[kc + 1][nr]);
    h.z = f2bf(tile[kc + 2][nr]);
    h.w = f2bf(tile[kc + 3][nr]);
    *(ushort4*)&out[(size_t)(n0 + nr) * K + k0 + kc] = h;
  }
}

// ---- prep: vb [bh][n][d] bf16 -> vtb [bh][d][n] bf16 (64x64 tiles) ----
__global__ __launch_bounds__(256) void transpose_v_kernel(
    const unsigned short* __restrict__ vb, unsigned short* __restrict__ vtb) {
  __shared__ u32 tile[64][65];
  const int tid = threadIdx.x;
  const int n0 = blockIdx.x * 64;
  const int bh = blockIdx.y;
  const size_t base = (size_t)bh * N_ * D_;
#pragma unroll
  for (int i = 0; i < 2; i++) {
    int id = i * 256 + tid;
    int row = id >> 3, c8 = id & 7;
    uint4 v = *(const uint4*)&vb[base + (size_t)(n0 + row) * D_ + c8 * 8];
    const unsigned short* pv = (const unsigned short*)&v;
#pragma unroll
    for (int j = 0; j < 8; j++) tile[row][c8 * 8 + j] = pv[j];
  }
  __syncthreads();
#pragma unroll
  for (int i = 0; i < 2; i++) {
    int id = i * 256 + tid;
    int d = id >> 3, nc = id & 7;
    uint4 o;
    unsigned short* po = (unsigned short*)&o;
#pragma unroll
    for (int j = 0; j < 8; j++) po[j] = (unsigned short)tile[nc * 8 + j][d];
    *(uint4*)&vtb[base + (size_t)d * N_ + n0 + nc * 8] = o;
  }
}

// ---- m97-class GEMM: C[M,Nout] = A[M,K] @ Bt[Nout,K]^T ----
// MODE 0: scatter bf16 to q/k/v [B,H,N,D]; q pre-scaled by 0.125*log2(e).
// MODE 1: fp32 out = acc + bias.
template<int MODE>
__global__ __launch_bounds__(256) void gemm128_kernel(
    const unsigned short* __restrict__ A, const unsigned short* __restrict__ Bt,
    const float* __restrict__ bias,
    unsigned short* __restrict__ qb, unsigned short* __restrict__ kb,
    unsigned short* __restrict__ vb, float* __restrict__ outp,
    int M, int K, int Nout)
{
  __shared__ unsigned short Al[128 * 64];
  __shared__ unsigned short Bl[128 * 64];
  const int tid = threadIdx.x;
  const int w = tid >> 6, lane = tid & 63;
  const int l15 = lane & 15, lk = lane >> 4;
  const int wr = w >> 1, wc = w & 1;
  const int n0 = blockIdx.x * 128, m0 = blockIdx.y * 128;
  const int srow = tid >> 3;
  const int scol = (tid & 7) * 8;

  f32x4 acc[4][4];
#pragma unroll
  for (int m = 0; m < 4; m++)
#pragma unroll
    for (int n = 0; n < 4; n++) acc[m][n] = f32x4{0.f, 0.f, 0.f, 0.f};

  for (int kt = 0; kt < K; kt += 64) {
#pragma unroll
    for (int i = 0; i < 4; i++)
      gld16(&A[(size_t)(m0 + i * 32 + srow) * K + kt + scol],
            &Al[i * 2048 + w * 512]);
#pragma unroll
    for (int i = 0; i < 4; i++)
      gld16(&Bt[(size_t)(n0 + i * 32 + srow) * K + kt + scol],
            &Bl[i * 2048 + w * 512]);
    __syncthreads();

#pragma unroll
    for (int kk = 0; kk < 2; kk++) {
      bf16x8 af[4], bf[4];
#pragma unroll
      for (int m = 0; m < 4; m++)
        af[m] = *(const bf16x8*)&Al[(wr * 64 + m * 16 + l15) * 64 + kk * 32 + lk * 8];
#pragma unroll
      for (int n = 0; n < 4; n++)
        bf[n] = *(const bf16x8*)&Bl[(wc * 64 + n * 16 + l15) * 64 + kk * 32 + lk * 8];
#pragma unroll
      for (int m = 0; m < 4; m++)
#pragma unroll
        for (int n = 0; n < 4; n++)
          acc[m][n] = __builtin_amdgcn_mfma_f32_16x16x32_bf16(af[m], bf[n], acc[m][n], 0, 0, 0);
    }
    __syncthreads();
  }

  if (MODE == 0) {
#pragma unroll
    for (int n = 0; n < 4; n++) {
      int c = n0 + wc * 64 + n * 16 + l15;
      int tsel = c >> 10, h = (c >> 6) & 15, d = c & 63;
      unsigned short* dst = (tsel == 0) ? qb : (tsel == 1 ? kb : vb);
      float sc = (tsel == 0) ? 0.125f * 1.44269504088896340736f : 1.0f;
#pragma unroll
      for (int m = 0; m < 4; m++) {
#pragma unroll
        for (int r = 0; r < 4; r++) {
          int row = m0 + wr * 64 + m * 16 + lk * 4 + r;
          int b = row >> 11, nn = row & 2047;
          dst[(((size_t)(b * 16 + h)) * 2048 + nn) * 64 + d] = f2bf(acc[m][n][r] * sc);
        }
      }
    }
  } else {
#pragma unroll
    for (int n = 0; n < 4; n++) {
      int c = n0 + wc * 64 + n * 16 + l15;
      float bv = bias[c];
#pragma unroll
      for (int m = 0; m < 4; m++) {
#pragma unroll
        for (int r = 0; r < 4; r++) {
          int row = m0 + wr * 64 + m * 16 + lk * 4 + r;
          outp[(size_t)row * Nout + c] = acc[m][n][r] + bv;
        }
      }
    }
  }
}

// ---- Flash attention: block = 64 Q rows of one (b,h), KVBLK=128. ----
// Staging via global_load_lds (no VGPR round-trip). Linear LDS tiles with
// both-sides XOR swizzle: LDS[row][col ^ ((row&7)<<3 elems)] holds
// global[row][col]; achieved by swizzling the SOURCE slot at stage time and
// XORing the read address (same involution both sides, rule 21).
__global__ __launch_bounds__(256) void flash_kernel(
    const unsigned short* __restrict__ qb, const unsigned short* __restrict__ kb,
    const unsigned short* __restrict__ vtb, unsigned short* __restrict__ ob)
{
  __shared__ unsigned short Kl[KVB * 64];   // [kv][d] linear 16 KB, swizzled
  __shared__ unsigned short Vl[64 * KVB];   // [d][kv] linear 16 KB, swizzled
  __shared__ unsigned short Pl[64][136];    // [qrow][kv] 17.4 KB (stride ok)
  const int tid = threadIdx.x;
  const int w = tid >> 6;
  const int lane = tid & 63;
  const int l15 = lane & 15, lk = lane >> 4;
  const int q0 = blockIdx.x * 64;
  const int bh = blockIdx.y;
  const size_t base = (size_t)bh * N_ * D_;
  const unsigned short* Qg = qb + base;
  const unsigned short* Kg = kb + base;
  const unsigned short* Vtg = vtb + base;   // [d][n]

  // staging source coords (pre-swizzled slots)
  // K: issue i covers rows i*32+(tid>>3); 8 slots of 16B per 128B row.
  const int k_r  = tid >> 3;
  const int k_sl = (tid & 7) ^ (k_r & 7);
  // Vt: issue i covers d-rows i*16+(tid>>4); 16 slots of 16B per 256B row;
  // swizzle the low 3 slot bits only.
  const int v_r  = tid >> 4;
  const int v_sl = ((tid & 15) & 8) | ((tid & 7) ^ (v_r & 7));

  bf16x8 qf[2];
#pragma unroll
  for (int kk = 0; kk < 2; kk++)
    qf[kk] = *(const bf16x8*)&Qg[(size_t)(q0 + w * 16 + l15) * 64 + kk * 32 + lk * 8];

  f32x4 acc_o[4];
#pragma unroll
  for (int i = 0; i < 4; i++) acc_o[i] = f32x4{0.f, 0.f, 0.f, 0.f};
  float mrow[4], lrow[4];
#pragma unroll
  for (int r = 0; r < 4; r++) { mrow[r] = -1e30f; lrow[r] = 0.f; }

  const int swz = (l15 & 7) << 3;   // read-side XOR (elems), row = *16 + l15

  for (int kv0 = 0; kv0 < N_; kv0 += KVB) {
    // ---- stage K[128][64] and Vt[64][128] via global_load_lds ----
#pragma unroll
    for (int i = 0; i < 4; i++)
      gld16(&Kg[(size_t)(kv0 + i * 32 + k_r) * 64 + k_sl * 8],
            &Kl[i * 2048 + w * 512]);
#pragma unroll
    for (int i = 0; i < 4; i++)
      gld16(&Vtg[(size_t)(i * 16 + v_r) * N_ + kv0 + v_sl * 8],
            &Vl[i * 2048 + w * 512]);
    __syncthreads();   // drains vmcnt (compiler) + all waves staged

    // S = Q K^T : 16 MFMA -> sa[8] (128 kv cols); S in log2-units
    f32x4 sa[8];
#pragma unroll
    for (int i = 0; i < 8; i++) sa[i] = f32x4{0.f, 0.f, 0.f, 0.f};
    __builtin_amdgcn_s_setprio(1);
#pragma unroll
    for (int kk = 0; kk < 2; kk++) {
#pragma unroll
      for (int nf = 0; nf < 8; nf++) {
        bf16x8 b = *(const bf16x8*)&Kl[(nf * 16 + l15) * 64 + ((kk * 32 + lk * 8) ^ swz)];
        sa[nf] = __builtin_amdgcn_mfma_f32_16x16x32_bf16(qf[kk], b, sa[nf], 0, 0, 0);
      }
    }
    __builtin_amdgcn_s_setprio(0);

    // online softmax (base-2): one update per 128 kv
#pragma unroll
    for (int r = 0; r < 4; r++) {
      float s0 = sa[0][r], s1 = sa[1][r], s2 = sa[2][r], s3 = sa[3][r];
      float s4 = sa[4][r], s5 = sa[5][r], s6 = sa[6][r], s7 = sa[7][r];
      float mx = fmaxf(fmaxf(fmaxf(s0, s1), fmaxf(s2, s3)),
                       fmaxf(fmaxf(s4, s5), fmaxf(s6, s7)));
      mx = fmaxf(mx, __shfl_xor(mx, 1));
      mx = fmaxf(mx, __shfl_xor(mx, 2));
      mx = fmaxf(mx, __shfl_xor(mx, 4));
      mx = fmaxf(mx, __shfl_xor(mx, 8));
      float mnew = fmaxf(mrow[r], mx);
      float corr = __builtin_amdgcn_exp2f(mrow[r] - mnew);
      float p0 = __builtin_amdgcn_exp2f(s0 - mnew);
      float p1 = __builtin_amdgcn_exp2f(s1 - mnew);
      float p2 = __builtin_amdgcn_exp2f(s2 - mnew);
      float p3 = __builtin_amdgcn_exp2f(s3 - mnew);
      float p4 = __builtin_amdgcn_exp2f(s4 - mnew);
      float p5 = __builtin_amdgcn_exp2f(s5 - mnew);
      float p6 = __builtin_amdgcn_exp2f(s6 - mnew);
      float p7 = __builtin_amdgcn_exp2f(s7 - mnew);
      float rs = ((p0 + p1) + (p2 + p3)) + ((p4 + p5) + (p6 + p7));
      rs += __shfl_xor(rs, 1);
      rs += __shfl_xor(rs, 2);
      rs += __shfl_xor(rs, 4);
      rs += __shfl_xor(rs, 8);
      lrow[r] = lrow[r] * corr + rs;
      mrow[r] = mnew;
#pragma unroll
      for (int nf = 0; nf < 4; nf++) acc_o[nf][r] *= corr;
      int prow = w * 16 + lk * 4 + r;
      Pl[prow][0   + l15] = f2bf(p0);
      Pl[prow][16  + l15] = f2bf(p1);
      Pl[prow][32  + l15] = f2bf(p2);
      Pl[prow][48  + l15] = f2bf(p3);
      Pl[prow][64  + l15] = f2bf(p4);
      Pl[prow][80  + l15] = f2bf(p5);
      Pl[prow][96  + l15] = f2bf(p6);
      Pl[prow][112 + l15] = f2bf(p7);
    }
    // no barrier: each wave reads only its OWN Pl rows (in-wave LDS ordering)

    // O += P V : 16 MFMA
    __builtin_amdgcn_s_setprio(1);
#pragma unroll
    for (int kk = 0; kk < 4; kk++) {
      bf16x8 a = *(const bf16x8*)&Pl[w * 16 + l15][kk * 32 + lk * 8];
#pragma unroll
      for (int nf = 0; nf < 4; nf++) {
        bf16x8 b = *(const bf16x8*)&Vl[(nf * 16 + l15) * 128 + ((kk * 32 + lk * 8) ^ swz)];
        acc_o[nf] = __builtin_amdgcn_mfma_f32_16x16x32_bf16(a, b, acc_o[nf], 0, 0, 0);
      }
    }
    __builtin_amdgcn_s_setprio(0);
    __syncthreads();   // all waves done reading Kl/Vl before next stage
  }

  const int b = bh >> 4, h = bh & 15;
#pragma unroll
  for (int r = 0; r < 4; r++) {
    float inv = 1.0f / lrow[r];
    int n = q0 + w * 16 + lk * 4 + r;
    size_t obase = (((size_t)b * N_ + n) * H_ + h) * D_;
#pragma unroll
    for (int nf = 0; nf < 4; nf++)
      ob[obase + nf * 16 + l15] = f2bf(acc_o[nf][r] * inv);
  }
}

extern "C" void kernel_launch(void* const* d_in, const int* in_sizes, int n_in,
                              void* d_out, int out_size, void* d_ws, size_t ws_size,
                              hipStream_t stream) {
  const float* x      = (const float*)d_in[0];
  const float* w_qkv  = (const float*)d_in[1];
  const float* w_proj = (const float*)d_in[2];
  const float* b_proj = (const float*)d_in[3];
  float* out = (float*)d_out;

  const size_t qsz = (size_t)B_ * H_ * N_ * D_;
  unsigned short* qb     = (unsigned short*)d_ws;
  unsigned short* kb     = qb + qsz;
  unsigned short* vb     = kb + qsz;
  unsigned short* vtb    = vb + qsz;
  unsigned short* xbf    = vtb + qsz;
  unsigned short* ob     = xbf;                           // alias: x dead after qkv
  unsigned short* wqkv_t = xbf + qsz;
  unsigned short* wproj_t= wqkv_t + (size_t)3072 * 1024;

  cvt_bf16_kernel<<<4096, 256, 0, stream>>>(x, xbf);
  transpose_cvt_kernel<<<dim3(3072 / 32, 1024 / 32), 256, 0, stream>>>(w_qkv, wqkv_t, 1024, 3072);
  transpose_cvt_kernel<<<dim3(1024 / 32, 1024 / 32), 256, 0, stream>>>(w_proj, wproj_t, 1024, 1024);

  gemm128_kernel<0><<<dim3(3072 / 128, 8192 / 128), 256, 0, stream>>>(
      xbf, wqkv_t, nullptr, qb, kb, vb, nullptr, 8192, 1024, 3072);

  transpose_v_kernel<<<dim3(N_ / 64, B_ * H_), 256, 0, stream>>>(vb, vtb);

  flash_kernel<<<dim3(N_ / 64, B_ * H_), 256, 0, stream>>>(qb, kb, vtb, ob);

  gemm128_kernel<1><<<dim3(1024 / 128, 8192 / 128), 256, 0, stream>>>(
      ob, wproj_t, b_proj, nullptr, nullptr, nullptr, out, 8192, 1024, 1024);
}